// Round 1
// baseline (1322.622 us; speedup 1.0000x reference)
//
#include <hip/hip_runtime.h>

#define Tt 2048
#define Cc 512
#define Bb 4
#define Hh 8
#define Dd 64

// ---------------------------------------------------------------------------
// Kernel 1: fused QKV GEMM (HS[8192,512] @ W[512,512]) + per-(b,channel)
// column sum-of-squares for pixel_norm (axis=1 = token axis).
// Block: 64x64 output tile, 256 threads, 4x4 micro-tile per thread, BK=16.
// ---------------------------------------------------------------------------
__global__ __launch_bounds__(256) void qkv_gemm(
    const float* __restrict__ HS,
    const float* __restrict__ Wq, const float* __restrict__ Wk,
    const float* __restrict__ Wv,
    float* __restrict__ Q, float* __restrict__ K, float* __restrict__ V,
    float* __restrict__ colsum)
{
    const int mt = blockIdx.x;      // 128 row tiles of 64
    const int nt = blockIdx.y;      // 8 col tiles of 64
    const int z  = blockIdx.z;      // 0=q 1=k 2=v
    const float* W  = (z == 0) ? Wq : (z == 1) ? Wk : Wv;
    float* Out      = (z == 0) ? Q  : (z == 1) ? K  : V;

    const int tid = threadIdx.x;
    const int tx = tid & 15, ty = tid >> 4;

    __shared__ float As[16][65];    // [k][m], pad: writes stride 65 -> no conflict
    __shared__ float Bs[16][65];    // [k][n]
    __shared__ float red[16][64];   // column sum-of-squares partials

    float acc[4][4] = {};

    const float* Abase = HS + (size_t)(mt * 64) * Cc;
    const float* Bbase = W + nt * 64;

    for (int k0 = 0; k0 < Cc; k0 += 16) {
        // A tile: 64 rows x 16 k (coalesced 16-wide along k)
        {
            const int k  = tid & 15;
            const int m0 = tid >> 4;
#pragma unroll
            for (int p = 0; p < 4; ++p) {
                const int m = m0 + p * 16;
                As[k][m] = Abase[(size_t)m * Cc + k0 + k];
            }
        }
        // B tile: 16 k x 64 n (coalesced 64-wide along n)
        {
            const int n  = tid & 63;
            const int kk = tid >> 6;
#pragma unroll
            for (int p = 0; p < 4; ++p) {
                const int k = kk + p * 4;
                Bs[k][n] = Bbase[(size_t)(k0 + k) * Cc + n];
            }
        }
        __syncthreads();
#pragma unroll
        for (int k = 0; k < 16; ++k) {
            float a[4], b[4];
#pragma unroll
            for (int i = 0; i < 4; ++i) a[i] = As[k][ty * 4 + i];
#pragma unroll
            for (int j = 0; j < 4; ++j) b[j] = Bs[k][tx * 4 + j];
#pragma unroll
            for (int i = 0; i < 4; ++i)
#pragma unroll
                for (int j = 0; j < 4; ++j)
                    acc[i][j] = fmaf(a[i], b[j], acc[i][j]);
        }
        __syncthreads();
    }

    // store results (float4-coalesced)
#pragma unroll
    for (int i = 0; i < 4; ++i) {
        float4 vst = make_float4(acc[i][0], acc[i][1], acc[i][2], acc[i][3]);
        *(float4*)&Out[(size_t)(mt * 64 + ty * 4 + i) * Cc + nt * 64 + tx * 4] = vst;
    }

    // column sum-of-squares over this tile's 64 rows -> atomicAdd per column
#pragma unroll
    for (int j = 0; j < 4; ++j) {
        float cp = acc[0][j] * acc[0][j] + acc[1][j] * acc[1][j] +
                   acc[2][j] * acc[2][j] + acc[3][j] * acc[3][j];
        red[ty][tx * 4 + j] = cp;
    }
    __syncthreads();
    if (tid < 64) {
        float s = 0.f;
#pragma unroll
        for (int t = 0; t < 16; ++t) s += red[t][tid];
        const int b = mt >> 5;      // 32 row-tiles per batch (2048/64)
        atomicAdd(&colsum[(size_t)z * (Bb * Cc) + b * Cc + nt * 64 + tid], s);
    }
}

// ---------------------------------------------------------------------------
// Kernel 2: colsum -> 1/sqrt(mean + eps)
// ---------------------------------------------------------------------------
__global__ void inv_norm_kernel(const float* __restrict__ colsum,
                                float* __restrict__ inv)
{
    const int i = blockIdx.x * blockDim.x + threadIdx.x;
    if (i < 3 * Bb * Cc)
        inv[i] = rsqrtf(colsum[i] * (1.0f / Tt) + 1e-4f);
}

// ---------------------------------------------------------------------------
// Kernel 3: flash-style attention per (b,h). 64-row Q tile per block,
// online softmax over 32 K/V tiles of 64. pixel_norm factors applied on
// LDS staging. 256 threads, 4x4 micro-tiles.
// ---------------------------------------------------------------------------
__global__ __launch_bounds__(256) void attn_kernel(
    const float* __restrict__ Q, const float* __restrict__ K,
    const float* __restrict__ V, const float* __restrict__ inv,
    float* __restrict__ O)
{
    const int qt = blockIdx.x;          // 32 q tiles
    const int bh = blockIdx.y;          // 32 (b,h)
    const int b = bh >> 3, h = bh & 7;
    const int tid = threadIdx.x;
    const int tx = tid & 15, ty = tid >> 4;

    __shared__ float Qs[64][65];
    __shared__ float Ks[64][65];
    __shared__ float Vs[64][65];
    __shared__ float Ss[64][65];
    __shared__ float mrow[64], lrow[64], arow[64];

    const float* iq = inv + 0 * (Bb * Cc) + b * Cc + h * 64;
    const float* ik = inv + 1 * (Bb * Cc) + b * Cc + h * 64;
    const float* iv = inv + 2 * (Bb * Cc) + b * Cc + h * 64;

    const float* qbase = Q + (size_t)(b * Tt + qt * 64) * Cc + h * 64;
#pragma unroll
    for (int i = 0; i < 16; ++i) {
        const int idx = tid + i * 256;
        const int r = idx >> 6, c = idx & 63;
        Qs[r][c] = qbase[(size_t)r * Cc + c] * iq[c];
    }
    if (tid < 64) { mrow[tid] = -1e30f; lrow[tid] = 0.f; }

    float o[4][4] = {};
    const float scale = 0.125f;     // 64^-0.5

    for (int kt = 0; kt < 32; ++kt) {
        const float* kbase = K + (size_t)(b * Tt + kt * 64) * Cc + h * 64;
        const float* vbase = V + (size_t)(b * Tt + kt * 64) * Cc + h * 64;
        __syncthreads();   // previous iteration's consumers done (and Q/m/l init)
#pragma unroll
        for (int i = 0; i < 16; ++i) {
            const int idx = tid + i * 256;
            const int r = idx >> 6, c = idx & 63;
            Ks[r][c] = kbase[(size_t)r * Cc + c] * ik[c];
            Vs[r][c] = vbase[(size_t)r * Cc + c] * iv[c];
        }
        __syncthreads();

        // S = scale * Qtile @ Ktile^T  (4x4 per thread)
        float s[4][4] = {};
#pragma unroll
        for (int d = 0; d < 64; ++d) {
            float qv[4], kv[4];
#pragma unroll
            for (int i = 0; i < 4; ++i) qv[i] = Qs[ty * 4 + i][d];
#pragma unroll
            for (int j = 0; j < 4; ++j) kv[j] = Ks[tx * 4 + j][d];
#pragma unroll
            for (int i = 0; i < 4; ++i)
#pragma unroll
                for (int j = 0; j < 4; ++j)
                    s[i][j] = fmaf(qv[i], kv[j], s[i][j]);
        }
#pragma unroll
        for (int i = 0; i < 4; ++i)
#pragma unroll
            for (int j = 0; j < 4; ++j)
                Ss[ty * 4 + i][tx * 4 + j] = s[i][j] * scale;
        __syncthreads();

        // online softmax row update (one thread per row)
        if (tid < 64) {
            const float m_old = mrow[tid];
            float m = m_old;
#pragma unroll 8
            for (int j = 0; j < 64; ++j) m = fmaxf(m, Ss[tid][j]);
            const float alpha = __expf(m_old - m);
            float ls = 0.f;
#pragma unroll 8
            for (int j = 0; j < 64; ++j) {
                const float p = __expf(Ss[tid][j] - m);
                Ss[tid][j] = p;
                ls += p;
            }
            mrow[tid] = m;
            lrow[tid] = lrow[tid] * alpha + ls;
            arow[tid] = alpha;
        }
        __syncthreads();

        // O = O * alpha(row) + P @ Vtile
        float ai[4];
#pragma unroll
        for (int i = 0; i < 4; ++i) ai[i] = arow[ty * 4 + i];
#pragma unroll
        for (int i = 0; i < 4; ++i)
#pragma unroll
            for (int j = 0; j < 4; ++j) o[i][j] *= ai[i];
#pragma unroll
        for (int k2 = 0; k2 < 64; ++k2) {
            float pv[4], vv[4];
#pragma unroll
            for (int i = 0; i < 4; ++i) pv[i] = Ss[ty * 4 + i][k2];
#pragma unroll
            for (int j = 0; j < 4; ++j) vv[j] = Vs[k2][tx * 4 + j];
#pragma unroll
            for (int i = 0; i < 4; ++i)
#pragma unroll
                for (int j = 0; j < 4; ++j)
                    o[i][j] = fmaf(pv[i], vv[j], o[i][j]);
        }
    }

    // write O / l  -> [B,T,C] layout (heads re-interleaved)
    float* obase = O + (size_t)(b * Tt + qt * 64) * Cc + h * 64;
#pragma unroll
    for (int i = 0; i < 4; ++i) {
        const int r = ty * 4 + i;
        const float li = 1.0f / lrow[r];
        float4 vst = make_float4(o[i][0] * li, o[i][1] * li,
                                 o[i][2] * li, o[i][3] * li);
        *(float4*)&obase[(size_t)r * Cc + tx * 4] = vst;
    }
}

// ---------------------------------------------------------------------------
// Kernel 4: out = attn @ Wo + bo + residual
// ---------------------------------------------------------------------------
__global__ __launch_bounds__(256) void out_gemm(
    const float* __restrict__ A, const float* __restrict__ Wo,
    const float* __restrict__ bo, const float* __restrict__ HS,
    float* __restrict__ Outp)
{
    const int mt = blockIdx.x;
    const int nt = blockIdx.y;
    const int tid = threadIdx.x;
    const int tx = tid & 15, ty = tid >> 4;

    __shared__ float As[16][65];
    __shared__ float Bs[16][65];

    float acc[4][4] = {};

    const float* Abase = A + (size_t)(mt * 64) * Cc;
    const float* Bbase = Wo + nt * 64;

    for (int k0 = 0; k0 < Cc; k0 += 16) {
        {
            const int k  = tid & 15;
            const int m0 = tid >> 4;
#pragma unroll
            for (int p = 0; p < 4; ++p) {
                const int m = m0 + p * 16;
                As[k][m] = Abase[(size_t)m * Cc + k0 + k];
            }
        }
        {
            const int n  = tid & 63;
            const int kk = tid >> 6;
#pragma unroll
            for (int p = 0; p < 4; ++p) {
                const int k = kk + p * 4;
                Bs[k][n] = Bbase[(size_t)(k0 + k) * Cc + n];
            }
        }
        __syncthreads();
#pragma unroll
        for (int k = 0; k < 16; ++k) {
            float a[4], b[4];
#pragma unroll
            for (int i = 0; i < 4; ++i) a[i] = As[k][ty * 4 + i];
#pragma unroll
            for (int j = 0; j < 4; ++j) b[j] = Bs[k][tx * 4 + j];
#pragma unroll
            for (int i = 0; i < 4; ++i)
#pragma unroll
                for (int j = 0; j < 4; ++j)
                    acc[i][j] = fmaf(a[i], b[j], acc[i][j]);
        }
        __syncthreads();
    }

#pragma unroll
    for (int i = 0; i < 4; ++i) {
        const size_t r = (size_t)(mt * 64 + ty * 4 + i);
        const int c0 = nt * 64 + tx * 4;
        float4 res = *(const float4*)&HS[r * Cc + c0];
        float4 bb  = *(const float4*)&bo[c0];
        float4 vst = make_float4(acc[i][0] + bb.x + res.x,
                                 acc[i][1] + bb.y + res.y,
                                 acc[i][2] + bb.z + res.z,
                                 acc[i][3] + bb.w + res.w);
        *(float4*)&Outp[r * Cc + c0] = vst;
    }
}

// ---------------------------------------------------------------------------
extern "C" void kernel_launch(void* const* d_in, const int* in_sizes, int n_in,
                              void* d_out, int out_size, void* d_ws,
                              size_t ws_size, hipStream_t stream)
{
    const float* HS = (const float*)d_in[0];
    const float* Wq = (const float*)d_in[1];
    const float* Wk = (const float*)d_in[2];
    const float* Wv = (const float*)d_in[3];
    const float* Wo = (const float*)d_in[4];
    const float* bo = (const float*)d_in[5];
    float* out = (float*)d_out;

    float* ws = (float*)d_ws;
    const size_t SZ = (size_t)Bb * Tt * Cc;     // 4,194,304 floats
    float* Qb = ws;
    float* Kb = ws + SZ;
    float* Vb = ws + 2 * SZ;
    float* AO = ws + 3 * SZ;
    float* colsum = ws + 4 * SZ;                // 3*B*C = 6144 floats
    float* inv    = colsum + 3 * Bb * Cc;       // 6144 floats

    hipMemsetAsync(colsum, 0, 3 * Bb * Cc * sizeof(float), stream);

    dim3 g1(128, 8, 3);
    qkv_gemm<<<g1, 256, 0, stream>>>(HS, Wq, Wk, Wv, Qb, Kb, Vb, colsum);

    inv_norm_kernel<<<(3 * Bb * Cc + 255) / 256, 256, 0, stream>>>(colsum, inv);

    dim3 g3(32, 32);
    attn_kernel<<<g3, 256, 0, stream>>>(Qb, Kb, Vb, inv, AO);

    dim3 g4(128, 8);
    out_gemm<<<g4, 256, 0, stream>>>(AO, Wo, bo, HS, out);
}

// Round 2
// 583.284 us; speedup vs baseline: 2.2675x; 2.2675x over previous
//
#include <hip/hip_runtime.h>

#define Tt 2048
#define Cc 512
#define Bb 4
#define Hh 8
#define BC (Bb * Cc)

typedef __attribute__((ext_vector_type(8))) short bf16x8;
typedef __attribute__((ext_vector_type(4))) float f32x4;

__device__ __forceinline__ short f2bf(float x) {
    union { float f; unsigned u; } v{x};
    unsigned r = v.u + 0x7FFF + ((v.u >> 16) & 1);
    return (short)(r >> 16);
}
__device__ __forceinline__ float bf2f(short h) {
    union { unsigned u; float f; } v{((unsigned)(unsigned short)h) << 16};
    return v.f;
}

// ---------------------------------------------------------------------------
// Kernel 1: fused QKV GEMM (fp32) + per-(b,channel) column sum-of-squares.
// (unchanged from R1 — proven correct)
// ---------------------------------------------------------------------------
__global__ __launch_bounds__(256) void qkv_gemm(
    const float* __restrict__ HS,
    const float* __restrict__ Wq, const float* __restrict__ Wk,
    const float* __restrict__ Wv,
    float* __restrict__ Q, float* __restrict__ K, float* __restrict__ V,
    float* __restrict__ colsum)
{
    const int mt = blockIdx.x, nt = blockIdx.y, z = blockIdx.z;
    const float* W = (z == 0) ? Wq : (z == 1) ? Wk : Wv;
    float* Out     = (z == 0) ? Q  : (z == 1) ? K  : V;

    const int tid = threadIdx.x;
    const int tx = tid & 15, ty = tid >> 4;

    __shared__ float As[16][65];
    __shared__ float Bs[16][65];
    __shared__ float red[16][64];

    float acc[4][4] = {};
    const float* Abase = HS + (size_t)(mt * 64) * Cc;
    const float* Bbase = W + nt * 64;

    for (int k0 = 0; k0 < Cc; k0 += 16) {
        {
            const int k = tid & 15, m0 = tid >> 4;
#pragma unroll
            for (int p = 0; p < 4; ++p)
                As[k][m0 + p * 16] = Abase[(size_t)(m0 + p * 16) * Cc + k0 + k];
        }
        {
            const int n = tid & 63, kk = tid >> 6;
#pragma unroll
            for (int p = 0; p < 4; ++p)
                Bs[kk + p * 4][n] = Bbase[(size_t)(k0 + kk + p * 4) * Cc + n];
        }
        __syncthreads();
#pragma unroll
        for (int k = 0; k < 16; ++k) {
            float a[4], b[4];
#pragma unroll
            for (int i = 0; i < 4; ++i) a[i] = As[k][ty * 4 + i];
#pragma unroll
            for (int j = 0; j < 4; ++j) b[j] = Bs[k][tx * 4 + j];
#pragma unroll
            for (int i = 0; i < 4; ++i)
#pragma unroll
                for (int j = 0; j < 4; ++j)
                    acc[i][j] = fmaf(a[i], b[j], acc[i][j]);
        }
        __syncthreads();
    }
#pragma unroll
    for (int i = 0; i < 4; ++i) {
        float4 vst = make_float4(acc[i][0], acc[i][1], acc[i][2], acc[i][3]);
        *(float4*)&Out[(size_t)(mt * 64 + ty * 4 + i) * Cc + nt * 64 + tx * 4] = vst;
    }
#pragma unroll
    for (int j = 0; j < 4; ++j)
        red[ty][tx * 4 + j] = acc[0][j] * acc[0][j] + acc[1][j] * acc[1][j] +
                              acc[2][j] * acc[2][j] + acc[3][j] * acc[3][j];
    __syncthreads();
    if (tid < 64) {
        float s = 0.f;
#pragma unroll
        for (int t = 0; t < 16; ++t) s += red[t][tid];
        atomicAdd(&colsum[(size_t)z * BC + (mt >> 5) * Cc + nt * 64 + tid], s);
    }
}

// ---------------------------------------------------------------------------
// Kernel 2: colsum -> 1/sqrt(mean + eps)
// ---------------------------------------------------------------------------
__global__ void inv_norm_kernel(const float* __restrict__ colsum,
                                float* __restrict__ inv)
{
    const int i = blockIdx.x * blockDim.x + threadIdx.x;
    if (i < 3 * BC) inv[i] = rsqrtf(colsum[i] * (1.0f / Tt) + 1e-4f);
}

// ---------------------------------------------------------------------------
// Kernel 3: V[b][t][c] -> VT[b][c][t] bf16, scaled by iv[b][c].
// LDS-tile transpose so both global read and write are coalesced.
// ---------------------------------------------------------------------------
__global__ __launch_bounds__(256) void norm_vt(
    const float* __restrict__ V, const float* __restrict__ inv,
    short* __restrict__ VT)
{
    const int blk = blockIdx.x;          // 4 * 8 * 32 = 1024
    const int b = blk >> 8, ct = (blk >> 5) & 7, tt = blk & 31;
    const int t0 = tt * 64, c0 = ct * 64;
    const int tid = threadIdx.x;

    __shared__ float tile[64][65];

#pragma unroll
    for (int i = 0; i < 4; ++i) {
        const int idx = i * 256 + tid;
        const int tr = idx >> 4, c4 = idx & 15;
        float4 v = *(const float4*)&V[(size_t)(b * Tt + t0 + tr) * Cc + c0 + c4 * 4];
        tile[tr][c4 * 4 + 0] = v.x; tile[tr][c4 * 4 + 1] = v.y;
        tile[tr][c4 * 4 + 2] = v.z; tile[tr][c4 * 4 + 3] = v.w;
    }
    __syncthreads();
#pragma unroll
    for (int i = 0; i < 4; ++i) {
        const int idx = i * 256 + tid;
        const int cr = idx >> 4, t4 = idx & 15;
        const float ivv = inv[2 * BC + b * Cc + c0 + cr];
        short4 o;
        o.x = f2bf(tile[t4 * 4 + 0][cr] * ivv);
        o.y = f2bf(tile[t4 * 4 + 1][cr] * ivv);
        o.z = f2bf(tile[t4 * 4 + 2][cr] * ivv);
        o.w = f2bf(tile[t4 * 4 + 3][cr] * ivv);
        *(short4*)&VT[(size_t)(b * Cc + c0 + cr) * Tt + t0 + t4 * 4] = o;
    }
}

// ---------------------------------------------------------------------------
// Kernel 4: MFMA flash attention. 64 Q-rows per block (4 waves x 16 rows),
// K-tiles of 64. QK^T = 3-term split-bf16 MFMA (fp32-level scores),
// softmax all-register via shfl_xor, PV = plain bf16 MFMA, fp32 accum.
// ---------------------------------------------------------------------------
#define LSTR 72   // LDS row stride in bf16 elems: 144 B = 16B-aligned, frag
                  // b128 reads hit the 8-words/bank floor (no excess conflict)

__global__ __launch_bounds__(256) void attn_mfma(
    const float* __restrict__ Q, const float* __restrict__ K,
    const short* __restrict__ VT, const float* __restrict__ inv,
    float* __restrict__ O)
{
    const int qt = blockIdx.x;            // 32
    const int bh = blockIdx.y;            // 32
    const int b = bh >> 3, h = bh & 7;
    const int tid = threadIdx.x;
    const int wave = tid >> 6, lane = tid & 63;
    const int quad = lane >> 4, lm = lane & 15;

    __shared__ short sKh[64 * LSTR];
    __shared__ short sKl[64 * LSTR];
    __shared__ short sVT[64 * LSTR];
    __shared__ short sP[4 * 16 * LSTR];
    short* myP = sP + wave * 16 * LSTR;

    // ---- Q fragments in registers (A-layout: m=lm, k=quad*8+j), scaled by
    // iq * 0.125 and split hi/lo. Held for all 32 K-tiles.
    bf16x8 qhi[2], qlo[2];
    {
        const int qrow = qt * 64 + wave * 16 + lm;
        const float* qp  = Q + (size_t)(b * Tt + qrow) * Cc + h * 64;
        const float* iqp = inv + b * Cc + h * 64;
#pragma unroll
        for (int ks = 0; ks < 2; ++ks) {
            const int d0 = ks * 32 + quad * 8;
            float4 a  = *(const float4*)&qp[d0];
            float4 b4 = *(const float4*)&qp[d0 + 4];
            float4 ia = *(const float4*)&iqp[d0];
            float4 ib = *(const float4*)&iqp[d0 + 4];
            float vals[8] = { a.x * ia.x, a.y * ia.y, a.z * ia.z, a.w * ia.w,
                              b4.x * ib.x, b4.y * ib.y, b4.z * ib.z, b4.w * ib.w };
#pragma unroll
            for (int j = 0; j < 8; ++j) {
                float v = vals[j] * 0.125f;
                short hi = f2bf(v);
                qhi[ks][j] = hi;
                qlo[ks][j] = f2bf(v - bf2f(hi));
            }
        }
    }

    // K-staging constants (channel factor fixed per thread across kt)
    const int sr = tid >> 2;              // not used; staging uses idx decode
    (void)sr;
    const float* ikp = inv + BC + b * Cc + h * 64;
    float4 ik4[1];
    {
        const int c4 = tid & 15;
        ik4[0] = *(const float4*)&ikp[c4 * 4];
    }

    f32x4 o[4];
#pragma unroll
    for (int nt = 0; nt < 4; ++nt) o[nt] = (f32x4){0.f, 0.f, 0.f, 0.f};
    float mr[4] = {-1e30f, -1e30f, -1e30f, -1e30f};
    float lr[4] = {0.f, 0.f, 0.f, 0.f};

    for (int kt = 0; kt < 32; ++kt) {
        __syncthreads();
        // ---- stage K (fp32 -> ik-scaled hi/lo bf16) and VT (pre-scaled bf16)
        {
            const float* gK = K + (size_t)(b * Tt + kt * 64) * Cc + h * 64;
            const short* gV = VT + (size_t)(b * Cc + h * 64) * Tt + kt * 64;
#pragma unroll
            for (int i = 0; i < 4; ++i) {
                const int idx = i * 256 + tid;
                const int r = idx >> 4, c4 = idx & 15;
                float4 kv = *(const float4*)&gK[(size_t)r * Cc + c4 * 4];
                float v0 = kv.x * ik4[0].x, v1 = kv.y * ik4[0].y;
                float v2 = kv.z * ik4[0].z, v3 = kv.w * ik4[0].w;
                short4 hh, ll;
                hh.x = f2bf(v0); ll.x = f2bf(v0 - bf2f(hh.x));
                hh.y = f2bf(v1); ll.y = f2bf(v1 - bf2f(hh.y));
                hh.z = f2bf(v2); ll.z = f2bf(v2 - bf2f(hh.z));
                hh.w = f2bf(v3); ll.w = f2bf(v3 - bf2f(hh.w));
                *(short4*)&sKh[r * LSTR + c4 * 4] = hh;
                *(short4*)&sKl[r * LSTR + c4 * 4] = ll;
                *(short4*)&sVT[r * LSTR + c4 * 4] =
                    *(const short4*)&gV[(size_t)r * Tt + c4 * 4];
            }
        }
        __syncthreads();

        // ---- S = Q K^T (compensated): 4 n-tiles x 2 k-steps x 3 mfma
        f32x4 sacc[4];
#pragma unroll
        for (int nt = 0; nt < 4; ++nt) sacc[nt] = (f32x4){0.f, 0.f, 0.f, 0.f};
#pragma unroll
        for (int nt = 0; nt < 4; ++nt) {
#pragma unroll
            for (int ks = 0; ks < 2; ++ks) {
                bf16x8 kh = *(const bf16x8*)&sKh[(16 * nt + lm) * LSTR + ks * 32 + quad * 8];
                bf16x8 kl = *(const bf16x8*)&sKl[(16 * nt + lm) * LSTR + ks * 32 + quad * 8];
                sacc[nt] = __builtin_amdgcn_mfma_f32_16x16x32_bf16(qhi[ks], kh, sacc[nt], 0, 0, 0);
                sacc[nt] = __builtin_amdgcn_mfma_f32_16x16x32_bf16(qhi[ks], kl, sacc[nt], 0, 0, 0);
                sacc[nt] = __builtin_amdgcn_mfma_f32_16x16x32_bf16(qlo[ks], kh, sacc[nt], 0, 0, 0);
            }
        }

        // ---- online softmax, all-register. Lane holds rows quad*4+r (C-layout),
        // keys = 16*nt + lm. Reduce over keys: in-lane over nt, shfl over lm.
        float alpha[4];
#pragma unroll
        for (int r = 0; r < 4; ++r) {
            float mx = fmaxf(fmaxf(sacc[0][r], sacc[1][r]),
                             fmaxf(sacc[2][r], sacc[3][r]));
#pragma unroll
            for (int msk = 1; msk < 16; msk <<= 1)
                mx = fmaxf(mx, __shfl_xor(mx, msk, 64));
            const float mnew = fmaxf(mr[r], mx);
            alpha[r] = __expf(mr[r] - mnew);
            mr[r] = mnew;
            float ps = 0.f;
#pragma unroll
            for (int nt = 0; nt < 4; ++nt) {
                float p = __expf(sacc[nt][r] - mnew);
                sacc[nt][r] = p;
                ps += p;
            }
#pragma unroll
            for (int msk = 1; msk < 16; msk <<= 1)
                ps += __shfl_xor(ps, msk, 64);
            lr[r] = lr[r] * alpha[r] + ps;
        }

        // ---- P (bf16) -> wave-private LDS, C-layout -> A-layout transform
#pragma unroll
        for (int nt = 0; nt < 4; ++nt)
#pragma unroll
            for (int r = 0; r < 4; ++r)
                myP[(quad * 4 + r) * LSTR + nt * 16 + lm] = f2bf(sacc[nt][r]);

        // ---- rescale O by alpha (rows quad*4+r match O's C-layout rows)
#pragma unroll
        for (int nt = 0; nt < 4; ++nt)
#pragma unroll
            for (int r = 0; r < 4; ++r) o[nt][r] *= alpha[r];

        // ---- O += P V
#pragma unroll
        for (int ks = 0; ks < 2; ++ks) {
            bf16x8 pa = *(const bf16x8*)&myP[lm * LSTR + ks * 32 + quad * 8];
#pragma unroll
            for (int nt = 0; nt < 4; ++nt) {
                bf16x8 vb = *(const bf16x8*)&sVT[(16 * nt + lm) * LSTR + ks * 32 + quad * 8];
                o[nt] = __builtin_amdgcn_mfma_f32_16x16x32_bf16(pa, vb, o[nt], 0, 0, 0);
            }
        }
    }

    // ---- epilogue: O /= l, write [B,T,C] with heads re-interleaved
    float il[4];
#pragma unroll
    for (int r = 0; r < 4; ++r) il[r] = 1.0f / lr[r];
#pragma unroll
    for (int nt = 0; nt < 4; ++nt)
#pragma unroll
        for (int r = 0; r < 4; ++r)
            O[(size_t)(b * Tt + qt * 64 + wave * 16 + quad * 4 + r) * Cc +
              h * 64 + nt * 16 + lm] = o[nt][r] * il[r];
}

// ---------------------------------------------------------------------------
// Kernel 5: out = attn @ Wo + bo + residual (unchanged)
// ---------------------------------------------------------------------------
__global__ __launch_bounds__(256) void out_gemm(
    const float* __restrict__ A, const float* __restrict__ Wo,
    const float* __restrict__ bo, const float* __restrict__ HS,
    float* __restrict__ Outp)
{
    const int mt = blockIdx.x, nt = blockIdx.y;
    const int tid = threadIdx.x;
    const int tx = tid & 15, ty = tid >> 4;

    __shared__ float As[16][65];
    __shared__ float Bs[16][65];

    float acc[4][4] = {};
    const float* Abase = A + (size_t)(mt * 64) * Cc;
    const float* Bbase = Wo + nt * 64;

    for (int k0 = 0; k0 < Cc; k0 += 16) {
        {
            const int k = tid & 15, m0 = tid >> 4;
#pragma unroll
            for (int p = 0; p < 4; ++p)
                As[k][m0 + p * 16] = Abase[(size_t)(m0 + p * 16) * Cc + k0 + k];
        }
        {
            const int n = tid & 63, kk = tid >> 6;
#pragma unroll
            for (int p = 0; p < 4; ++p)
                Bs[kk + p * 4][n] = Bbase[(size_t)(k0 + kk + p * 4) * Cc + n];
        }
        __syncthreads();
#pragma unroll
        for (int k = 0; k < 16; ++k) {
            float a[4], b[4];
#pragma unroll
            for (int i = 0; i < 4; ++i) a[i] = As[k][ty * 4 + i];
#pragma unroll
            for (int j = 0; j < 4; ++j) b[j] = Bs[k][tx * 4 + j];
#pragma unroll
            for (int i = 0; i < 4; ++i)
#pragma unroll
                for (int j = 0; j < 4; ++j)
                    acc[i][j] = fmaf(a[i], b[j], acc[i][j]);
        }
        __syncthreads();
    }
#pragma unroll
    for (int i = 0; i < 4; ++i) {
        const size_t r = (size_t)(mt * 64 + ty * 4 + i);
        const int c0 = nt * 64 + tx * 4;
        float4 res = *(const float4*)&HS[r * Cc + c0];
        float4 bb  = *(const float4*)&bo[c0];
        float4 vst = make_float4(acc[i][0] + bb.x + res.x,
                                 acc[i][1] + bb.y + res.y,
                                 acc[i][2] + bb.z + res.z,
                                 acc[i][3] + bb.w + res.w);
        *(float4*)&Outp[r * Cc + c0] = vst;
    }
}

// ---------------------------------------------------------------------------
extern "C" void kernel_launch(void* const* d_in, const int* in_sizes, int n_in,
                              void* d_out, int out_size, void* d_ws,
                              size_t ws_size, hipStream_t stream)
{
    const float* HS = (const float*)d_in[0];
    const float* Wq = (const float*)d_in[1];
    const float* Wk = (const float*)d_in[2];
    const float* Wv = (const float*)d_in[3];
    const float* Wo = (const float*)d_in[4];
    const float* bo = (const float*)d_in[5];
    float* out = (float*)d_out;

    float* ws = (float*)d_ws;
    const size_t SZ = (size_t)Bb * Tt * Cc;      // 4,194,304 floats
    float* Qb = ws;                               // [0, SZ)
    float* Kb = ws + SZ;                          // [SZ, 2SZ)
    float* Vb = ws + 2 * SZ;                      // [2SZ, 3SZ) fp32 V
    float* AO = Vb;                               // aliases Vb (dead after norm_vt)
    short* VTh = (short*)(ws + 3 * SZ);           // SZ bf16 = SZ/2 floats
    float* colsum = ws + 3 * SZ + SZ / 2;         // 3*B*C
    float* inv    = colsum + 3 * BC;

    hipMemsetAsync(colsum, 0, 3 * BC * sizeof(float), stream);

    dim3 g1(128, 8, 3);
    qkv_gemm<<<g1, 256, 0, stream>>>(HS, Wq, Wk, Wv, Qb, Kb, Vb, colsum);

    inv_norm_kernel<<<(3 * BC + 255) / 256, 256, 0, stream>>>(colsum, inv);

    norm_vt<<<1024, 256, 0, stream>>>(Vb, inv, VTh);

    dim3 g3(32, 32);
    attn_mfma<<<g3, 256, 0, stream>>>(Qb, Kb, VTh, inv, AO);

    dim3 g4(128, 8);
    out_gemm<<<g4, 256, 0, stream>>>(AO, Wo, bo, HS, out);
}

// Round 3
// 322.274 us; speedup vs baseline: 4.1040x; 1.8099x over previous
//
#include <hip/hip_runtime.h>

#define Tt 2048
#define Cc 512
#define Bb 4
#define BC (Bb * Cc)

typedef __attribute__((ext_vector_type(8))) short bf16x8;
typedef __attribute__((ext_vector_type(4))) float f32x4;

__device__ __forceinline__ short f2bf(float x) {
    union { float f; unsigned u; } v{x};
    unsigned r = v.u + 0x7FFF + ((v.u >> 16) & 1);
    return (short)(r >> 16);
}
__device__ __forceinline__ float bf2f(short h) {
    union { unsigned u; float f; } v{((unsigned)(unsigned short)h) << 16};
    return v.f;
}
__device__ __forceinline__ void split2(float x, short& h, short& l) {
    h = f2bf(x);
    l = f2bf(x - bf2f(h));
}

// ---------------------------------------------------------------------------
// Kernel 0: W[k][n] (x4: Wq,Wk,Wv,Wo) -> Wt[z][n][k] split hi/lo bf16.
// ---------------------------------------------------------------------------
__global__ __launch_bounds__(256) void wsetup(
    const float* __restrict__ Wq, const float* __restrict__ Wk,
    const float* __restrict__ Wv, const float* __restrict__ Wo,
    short* __restrict__ Wth, short* __restrict__ Wtl)
{
    const int z = blockIdx.y;
    const float* W = (z == 0) ? Wq : (z == 1) ? Wk : (z == 2) ? Wv : Wo;
    const int k0 = (blockIdx.x >> 3) * 64, n0 = (blockIdx.x & 7) * 64;
    const int tid = threadIdx.x;
    __shared__ float tile[64][65];

#pragma unroll
    for (int i = 0; i < 4; ++i) {
        const int idx = i * 256 + tid;
        const int kr = idx >> 4, c4 = idx & 15;
        float4 v = *(const float4*)&W[(size_t)(k0 + kr) * Cc + n0 + c4 * 4];
        tile[kr][c4 * 4 + 0] = v.x; tile[kr][c4 * 4 + 1] = v.y;
        tile[kr][c4 * 4 + 2] = v.z; tile[kr][c4 * 4 + 3] = v.w;
    }
    __syncthreads();
#pragma unroll
    for (int i = 0; i < 4; ++i) {
        const int idx = i * 256 + tid;
        const int nr = idx >> 4, k4 = idx & 15;
        short4 h, l;
        split2(tile[k4 * 4 + 0][nr], h.x, l.x);
        split2(tile[k4 * 4 + 1][nr], h.y, l.y);
        split2(tile[k4 * 4 + 2][nr], h.z, l.z);
        split2(tile[k4 * 4 + 3][nr], h.w, l.w);
        const size_t base = ((size_t)(z * 512 + n0 + nr)) * Cc + k0 + k4 * 4;
        *(short4*)&Wth[base] = h;
        *(short4*)&Wtl[base] = l;
    }
}

// ---------------------------------------------------------------------------
// Kernel 1: QKV GEMM via compensated split-bf16 MFMA. 128x128 tile, 4 waves
// (each 64x64 = 4x4 frags of 16x16x32). BK=32. Epilogue: fp32 store +
// per-(b,channel) column sum-of-squares atomics.
// ---------------------------------------------------------------------------
__global__ __launch_bounds__(256, 3) void qkv_mfma(
    const float* __restrict__ HS, const short* __restrict__ Wth,
    const short* __restrict__ Wtl,
    float* __restrict__ Q, float* __restrict__ K, float* __restrict__ V,
    float* __restrict__ colsum)
{
    const int mt = blockIdx.x;              // 64
    const int nt = blockIdx.y;              // 4
    const int z  = blockIdx.z;              // 3
    float* Out = (z == 0) ? Q : (z == 1) ? K : V;

    const int tid = threadIdx.x;
    const int wave = tid >> 6, lane = tid & 63;
    const int quad = lane >> 4, lm = lane & 15;
    const int wm = (wave & 1) * 64, wn = (wave >> 1) * 64;

    __shared__ short sAh[128 * 40], sAl[128 * 40];
    __shared__ short sBh[128 * 40], sBl[128 * 40];

    f32x4 acc[4][4];
#pragma unroll
    for (int mf = 0; mf < 4; ++mf)
#pragma unroll
        for (int nf = 0; nf < 4; ++nf) acc[mf][nf] = (f32x4){0.f, 0.f, 0.f, 0.f};

    const int r2 = tid >> 1, kc = (tid & 1) * 16;
    const float* ga  = HS + (size_t)(mt * 128 + r2) * Cc + kc;
    const short* gbh = Wth + ((size_t)(z * 512 + nt * 128 + r2)) * Cc + kc;
    const short* gbl = Wtl + ((size_t)(z * 512 + nt * 128 + r2)) * Cc + kc;

    for (int k0 = 0; k0 < Cc; k0 += 32) {
        __syncthreads();
        // stage A (fp32 -> hi/lo bf16)
#pragma unroll
        for (int j = 0; j < 4; ++j) {
            float4 a = *(const float4*)&ga[k0 + j * 4];
            short4 h, l;
            split2(a.x, h.x, l.x); split2(a.y, h.y, l.y);
            split2(a.z, h.z, l.z); split2(a.w, h.w, l.w);
            *(short4*)&sAh[r2 * 40 + kc + j * 4] = h;
            *(short4*)&sAl[r2 * 40 + kc + j * 4] = l;
        }
        // stage B (pre-split bf16, straight copy)
        {
            bf16x8 b0 = *(const bf16x8*)&gbh[k0];
            bf16x8 b1 = *(const bf16x8*)&gbh[k0 + 8];
            bf16x8 c0 = *(const bf16x8*)&gbl[k0];
            bf16x8 c1 = *(const bf16x8*)&gbl[k0 + 8];
            *(bf16x8*)&sBh[r2 * 40 + kc]     = b0;
            *(bf16x8*)&sBh[r2 * 40 + kc + 8] = b1;
            *(bf16x8*)&sBl[r2 * 40 + kc]     = c0;
            *(bf16x8*)&sBl[r2 * 40 + kc + 8] = c1;
        }
        __syncthreads();

        bf16x8 ah[4], al[4], bh[4], bl[4];
#pragma unroll
        for (int mf = 0; mf < 4; ++mf) {
            ah[mf] = *(const bf16x8*)&sAh[(wm + mf * 16 + lm) * 40 + quad * 8];
            al[mf] = *(const bf16x8*)&sAl[(wm + mf * 16 + lm) * 40 + quad * 8];
        }
#pragma unroll
        for (int nf = 0; nf < 4; ++nf) {
            bh[nf] = *(const bf16x8*)&sBh[(wn + nf * 16 + lm) * 40 + quad * 8];
            bl[nf] = *(const bf16x8*)&sBl[(wn + nf * 16 + lm) * 40 + quad * 8];
        }
#pragma unroll
        for (int mf = 0; mf < 4; ++mf)
#pragma unroll
            for (int nf = 0; nf < 4; ++nf) {
                acc[mf][nf] = __builtin_amdgcn_mfma_f32_16x16x32_bf16(ah[mf], bh[nf], acc[mf][nf], 0, 0, 0);
                acc[mf][nf] = __builtin_amdgcn_mfma_f32_16x16x32_bf16(ah[mf], bl[nf], acc[mf][nf], 0, 0, 0);
                acc[mf][nf] = __builtin_amdgcn_mfma_f32_16x16x32_bf16(al[mf], bh[nf], acc[mf][nf], 0, 0, 0);
            }
    }

    // epilogue: store fp32 + column sum-of-squares
    const int bidx = mt >> 4;               // 16 m-tiles per batch
#pragma unroll
    for (int nf = 0; nf < 4; ++nf) {
        float cs = 0.f;
#pragma unroll
        for (int mf = 0; mf < 4; ++mf)
#pragma unroll
            for (int r = 0; r < 4; ++r) {
                const float v = acc[mf][nf][r];
                Out[(size_t)(mt * 128 + wm + mf * 16 + quad * 4 + r) * Cc +
                    nt * 128 + wn + nf * 16 + lm] = v;
                cs += v * v;
            }
        cs += __shfl_xor(cs, 16, 64);
        cs += __shfl_xor(cs, 32, 64);
        if (lane < 16)
            atomicAdd(&colsum[(size_t)z * BC + bidx * Cc + nt * 128 + wn + nf * 16 + lane], cs);
    }
}

// ---------------------------------------------------------------------------
// Kernel 2: colsum -> 1/sqrt(mean + eps)
// ---------------------------------------------------------------------------
__global__ void inv_norm_kernel(const float* __restrict__ colsum,
                                float* __restrict__ inv)
{
    const int i = blockIdx.x * blockDim.x + threadIdx.x;
    if (i < 3 * BC) inv[i] = rsqrtf(colsum[i] * (1.0f / Tt) + 1e-4f);
}

// ---------------------------------------------------------------------------
// Kernel 3: V[b][t][c] -> VT[b][c][t] bf16, scaled by iv[b][c].
// ---------------------------------------------------------------------------
__global__ __launch_bounds__(256) void norm_vt(
    const float* __restrict__ V, const float* __restrict__ inv,
    short* __restrict__ VT)
{
    const int blk = blockIdx.x;
    const int b = blk >> 8, ct = (blk >> 5) & 7, tt = blk & 31;
    const int t0 = tt * 64, c0 = ct * 64;
    const int tid = threadIdx.x;

    __shared__ float tile[64][65];

#pragma unroll
    for (int i = 0; i < 4; ++i) {
        const int idx = i * 256 + tid;
        const int tr = idx >> 4, c4 = idx & 15;
        float4 v = *(const float4*)&V[(size_t)(b * Tt + t0 + tr) * Cc + c0 + c4 * 4];
        tile[tr][c4 * 4 + 0] = v.x; tile[tr][c4 * 4 + 1] = v.y;
        tile[tr][c4 * 4 + 2] = v.z; tile[tr][c4 * 4 + 3] = v.w;
    }
    __syncthreads();
#pragma unroll
    for (int i = 0; i < 4; ++i) {
        const int idx = i * 256 + tid;
        const int cr = idx >> 4, t4 = idx & 15;
        const float ivv = inv[2 * BC + b * Cc + c0 + cr];
        short4 o;
        o.x = f2bf(tile[t4 * 4 + 0][cr] * ivv);
        o.y = f2bf(tile[t4 * 4 + 1][cr] * ivv);
        o.z = f2bf(tile[t4 * 4 + 2][cr] * ivv);
        o.w = f2bf(tile[t4 * 4 + 3][cr] * ivv);
        *(short4*)&VT[(size_t)(b * Cc + c0 + cr) * Tt + t0 + t4 * 4] = o;
    }
}

// ---------------------------------------------------------------------------
// Kernel 4: MFMA flash attention (as R2), epilogue now writes AO hi/lo bf16.
// ---------------------------------------------------------------------------
#define LSTR 72

__global__ __launch_bounds__(256) void attn_mfma(
    const float* __restrict__ Q, const float* __restrict__ K,
    const short* __restrict__ VT, const float* __restrict__ inv,
    short* __restrict__ AOh, short* __restrict__ AOl)
{
    const int qt = blockIdx.x;
    const int bh = blockIdx.y;
    const int b = bh >> 3, h = bh & 7;
    const int tid = threadIdx.x;
    const int wave = tid >> 6, lane = tid & 63;
    const int quad = lane >> 4, lm = lane & 15;

    __shared__ short sKh[64 * LSTR];
    __shared__ short sKl[64 * LSTR];
    __shared__ short sVT[64 * LSTR];
    __shared__ short sP[4 * 16 * LSTR];
    short* myP = sP + wave * 16 * LSTR;

    bf16x8 qhi[2], qlo[2];
    {
        const int qrow = qt * 64 + wave * 16 + lm;
        const float* qp  = Q + (size_t)(b * Tt + qrow) * Cc + h * 64;
        const float* iqp = inv + b * Cc + h * 64;
#pragma unroll
        for (int ks = 0; ks < 2; ++ks) {
            const int d0 = ks * 32 + quad * 8;
            float4 a  = *(const float4*)&qp[d0];
            float4 b4 = *(const float4*)&qp[d0 + 4];
            float4 ia = *(const float4*)&iqp[d0];
            float4 ib = *(const float4*)&iqp[d0 + 4];
            float vals[8] = { a.x * ia.x, a.y * ia.y, a.z * ia.z, a.w * ia.w,
                              b4.x * ib.x, b4.y * ib.y, b4.z * ib.z, b4.w * ib.w };
#pragma unroll
            for (int j = 0; j < 8; ++j) {
                float v = vals[j] * 0.125f;
                short hi = f2bf(v);
                qhi[ks][j] = hi;
                qlo[ks][j] = f2bf(v - bf2f(hi));
            }
        }
    }

    const float* ikp = inv + BC + b * Cc + h * 64;
    float4 ik4;
    {
        const int c4 = tid & 15;
        ik4 = *(const float4*)&ikp[c4 * 4];
    }

    f32x4 o[4];
#pragma unroll
    for (int nt = 0; nt < 4; ++nt) o[nt] = (f32x4){0.f, 0.f, 0.f, 0.f};
    float mr[4] = {-1e30f, -1e30f, -1e30f, -1e30f};
    float lr[4] = {0.f, 0.f, 0.f, 0.f};

    for (int kt = 0; kt < 32; ++kt) {
        __syncthreads();
        {
            const float* gK = K + (size_t)(b * Tt + kt * 64) * Cc + h * 64;
            const short* gV = VT + (size_t)(b * Cc + h * 64) * Tt + kt * 64;
#pragma unroll
            for (int i = 0; i < 4; ++i) {
                const int idx = i * 256 + tid;
                const int r = idx >> 4, c4 = idx & 15;
                float4 kv = *(const float4*)&gK[(size_t)r * Cc + c4 * 4];
                float v0 = kv.x * ik4.x, v1 = kv.y * ik4.y;
                float v2 = kv.z * ik4.z, v3 = kv.w * ik4.w;
                short4 hh, ll;
                split2(v0, hh.x, ll.x); split2(v1, hh.y, ll.y);
                split2(v2, hh.z, ll.z); split2(v3, hh.w, ll.w);
                *(short4*)&sKh[r * LSTR + c4 * 4] = hh;
                *(short4*)&sKl[r * LSTR + c4 * 4] = ll;
                *(short4*)&sVT[r * LSTR + c4 * 4] =
                    *(const short4*)&gV[(size_t)r * Tt + c4 * 4];
            }
        }
        __syncthreads();

        f32x4 sacc[4];
#pragma unroll
        for (int nt = 0; nt < 4; ++nt) sacc[nt] = (f32x4){0.f, 0.f, 0.f, 0.f};
#pragma unroll
        for (int nt = 0; nt < 4; ++nt) {
#pragma unroll
            for (int ks = 0; ks < 2; ++ks) {
                bf16x8 kh = *(const bf16x8*)&sKh[(16 * nt + lm) * LSTR + ks * 32 + quad * 8];
                bf16x8 kl = *(const bf16x8*)&sKl[(16 * nt + lm) * LSTR + ks * 32 + quad * 8];
                sacc[nt] = __builtin_amdgcn_mfma_f32_16x16x32_bf16(qhi[ks], kh, sacc[nt], 0, 0, 0);
                sacc[nt] = __builtin_amdgcn_mfma_f32_16x16x32_bf16(qhi[ks], kl, sacc[nt], 0, 0, 0);
                sacc[nt] = __builtin_amdgcn_mfma_f32_16x16x32_bf16(qlo[ks], kh, sacc[nt], 0, 0, 0);
            }
        }

        float alpha[4];
#pragma unroll
        for (int r = 0; r < 4; ++r) {
            float mx = fmaxf(fmaxf(sacc[0][r], sacc[1][r]),
                             fmaxf(sacc[2][r], sacc[3][r]));
#pragma unroll
            for (int msk = 1; msk < 16; msk <<= 1)
                mx = fmaxf(mx, __shfl_xor(mx, msk, 64));
            const float mnew = fmaxf(mr[r], mx);
            alpha[r] = __expf(mr[r] - mnew);
            mr[r] = mnew;
            float ps = 0.f;
#pragma unroll
            for (int nt = 0; nt < 4; ++nt) {
                float p = __expf(sacc[nt][r] - mnew);
                sacc[nt][r] = p;
                ps += p;
            }
#pragma unroll
            for (int msk = 1; msk < 16; msk <<= 1)
                ps += __shfl_xor(ps, msk, 64);
            lr[r] = lr[r] * alpha[r] + ps;
        }

#pragma unroll
        for (int nt = 0; nt < 4; ++nt)
#pragma unroll
            for (int r = 0; r < 4; ++r)
                myP[(quad * 4 + r) * LSTR + nt * 16 + lm] = f2bf(sacc[nt][r]);

#pragma unroll
        for (int nt = 0; nt < 4; ++nt)
#pragma unroll
            for (int r = 0; r < 4; ++r) o[nt][r] *= alpha[r];

#pragma unroll
        for (int ks = 0; ks < 2; ++ks) {
            bf16x8 pa = *(const bf16x8*)&myP[lm * LSTR + ks * 32 + quad * 8];
#pragma unroll
            for (int nt = 0; nt < 4; ++nt) {
                bf16x8 vb = *(const bf16x8*)&sVT[(16 * nt + lm) * LSTR + ks * 32 + quad * 8];
                o[nt] = __builtin_amdgcn_mfma_f32_16x16x32_bf16(pa, vb, o[nt], 0, 0, 0);
            }
        }
    }

    float il[4];
#pragma unroll
    for (int r = 0; r < 4; ++r) il[r] = 1.0f / lr[r];
#pragma unroll
    for (int nt = 0; nt < 4; ++nt)
#pragma unroll
        for (int r = 0; r < 4; ++r) {
            const float v = o[nt][r] * il[r];
            const size_t idx =
                (size_t)(b * Tt + qt * 64 + wave * 16 + quad * 4 + r) * Cc +
                h * 64 + nt * 16 + lm;
            short hi = f2bf(v);
            AOh[idx] = hi;
            AOl[idx] = f2bf(v - bf2f(hi));
        }
}

// ---------------------------------------------------------------------------
// Kernel 5: out = AO @ Wo + bo + residual, compensated MFMA. 64x128 tile,
// 4 waves (each 32x64). A pre-split (AOh/AOl), B pre-split (Wt z=3).
// ---------------------------------------------------------------------------
__global__ __launch_bounds__(256, 2) void out_mfma(
    const short* __restrict__ AOh, const short* __restrict__ AOl,
    const short* __restrict__ Wth, const short* __restrict__ Wtl,
    const float* __restrict__ bo, const float* __restrict__ HS,
    float* __restrict__ Outp)
{
    const int mt = blockIdx.x;              // 128
    const int nt = blockIdx.y;              // 4
    const int tid = threadIdx.x;
    const int wave = tid >> 6, lane = tid & 63;
    const int quad = lane >> 4, lm = lane & 15;
    const int wm = (wave & 1) * 32, wn = (wave >> 1) * 64;

    __shared__ short sAh[64 * 40], sAl[64 * 40];
    __shared__ short sBh[128 * 40], sBl[128 * 40];

    f32x4 acc[2][4];
#pragma unroll
    for (int mf = 0; mf < 2; ++mf)
#pragma unroll
        for (int nf = 0; nf < 4; ++nf) acc[mf][nf] = (f32x4){0.f, 0.f, 0.f, 0.f};

    const int ra = tid >> 2, ka = (tid & 3) * 8;
    const int rb = tid >> 1, kb = (tid & 1) * 16;
    const short* gah = AOh + (size_t)(mt * 64 + ra) * Cc + ka;
    const short* gal = AOl + (size_t)(mt * 64 + ra) * Cc + ka;
    const short* gbh = Wth + ((size_t)(3 * 512 + nt * 128 + rb)) * Cc + kb;
    const short* gbl = Wtl + ((size_t)(3 * 512 + nt * 128 + rb)) * Cc + kb;

    for (int k0 = 0; k0 < Cc; k0 += 32) {
        __syncthreads();
        {
            bf16x8 a0 = *(const bf16x8*)&gah[k0];
            bf16x8 a1 = *(const bf16x8*)&gal[k0];
            *(bf16x8*)&sAh[ra * 40 + ka] = a0;
            *(bf16x8*)&sAl[ra * 40 + ka] = a1;
            bf16x8 b0 = *(const bf16x8*)&gbh[k0];
            bf16x8 b1 = *(const bf16x8*)&gbh[k0 + 8];
            bf16x8 c0 = *(const bf16x8*)&gbl[k0];
            bf16x8 c1 = *(const bf16x8*)&gbl[k0 + 8];
            *(bf16x8*)&sBh[rb * 40 + kb]     = b0;
            *(bf16x8*)&sBh[rb * 40 + kb + 8] = b1;
            *(bf16x8*)&sBl[rb * 40 + kb]     = c0;
            *(bf16x8*)&sBl[rb * 40 + kb + 8] = c1;
        }
        __syncthreads();

        bf16x8 ah[2], al[2], bh[4], bl[4];
#pragma unroll
        for (int mf = 0; mf < 2; ++mf) {
            ah[mf] = *(const bf16x8*)&sAh[(wm + mf * 16 + lm) * 40 + quad * 8];
            al[mf] = *(const bf16x8*)&sAl[(wm + mf * 16 + lm) * 40 + quad * 8];
        }
#pragma unroll
        for (int nf = 0; nf < 4; ++nf) {
            bh[nf] = *(const bf16x8*)&sBh[(wn + nf * 16 + lm) * 40 + quad * 8];
            bl[nf] = *(const bf16x8*)&sBl[(wn + nf * 16 + lm) * 40 + quad * 8];
        }
#pragma unroll
        for (int mf = 0; mf < 2; ++mf)
#pragma unroll
            for (int nf = 0; nf < 4; ++nf) {
                acc[mf][nf] = __builtin_amdgcn_mfma_f32_16x16x32_bf16(ah[mf], bh[nf], acc[mf][nf], 0, 0, 0);
                acc[mf][nf] = __builtin_amdgcn_mfma_f32_16x16x32_bf16(ah[mf], bl[nf], acc[mf][nf], 0, 0, 0);
                acc[mf][nf] = __builtin_amdgcn_mfma_f32_16x16x32_bf16(al[mf], bh[nf], acc[mf][nf], 0, 0, 0);
            }
    }

#pragma unroll
    for (int mf = 0; mf < 2; ++mf)
#pragma unroll
        for (int r = 0; r < 4; ++r) {
            const size_t m = (size_t)(mt * 64 + wm + mf * 16 + quad * 4 + r);
#pragma unroll
            for (int nf = 0; nf < 4; ++nf) {
                const int col = nt * 128 + wn + nf * 16 + lm;
                Outp[m * Cc + col] = acc[mf][nf][r] + bo[col] + HS[m * Cc + col];
            }
        }
}

// ---------------------------------------------------------------------------
extern "C" void kernel_launch(void* const* d_in, const int* in_sizes, int n_in,
                              void* d_out, int out_size, void* d_ws,
                              size_t ws_size, hipStream_t stream)
{
    const float* HS = (const float*)d_in[0];
    const float* Wq = (const float*)d_in[1];
    const float* Wk = (const float*)d_in[2];
    const float* Wv = (const float*)d_in[3];
    const float* Wo = (const float*)d_in[4];
    const float* bo = (const float*)d_in[5];
    float* out = (float*)d_out;

    float* ws = (float*)d_ws;
    const size_t SZ = (size_t)Bb * Tt * Cc;        // 4,194,304 floats
    float* Qb = ws;                                 // fp32
    float* Kb = ws + SZ;                            // fp32
    float* Vb = ws + 2 * SZ;                        // fp32; dead after norm_vt
    short* AOh = (short*)Vb;                        // aliases Vb
    short* AOl = AOh + SZ;
    short* VTh = (short*)(ws + 3 * SZ);             // SZ shorts
    short* Wth = (short*)(ws + 3 * SZ + SZ / 2);    // 4*512*512 shorts
    short* Wtl = Wth + 4 * Cc * Cc;
    float* colsum = ws + 3 * SZ + SZ / 2 + (4 * Cc * Cc); // = + 2*524288 floats
    float* inv    = colsum + 3 * BC;

    hipMemsetAsync(colsum, 0, 3 * BC * sizeof(float), stream);

    wsetup<<<dim3(64, 4), 256, 0, stream>>>(Wq, Wk, Wv, Wo, Wth, Wtl);

    qkv_mfma<<<dim3(64, 4, 3), 256, 0, stream>>>(HS, Wth, Wtl, Qb, Kb, Vb, colsum);

    inv_norm_kernel<<<(3 * BC + 255) / 256, 256, 0, stream>>>(colsum, inv);

    norm_vt<<<1024, 256, 0, stream>>>(Vb, inv, VTh);

    attn_mfma<<<dim3(32, 32), 256, 0, stream>>>(Qb, Kb, VTh, inv, AOh, AOl);

    out_mfma<<<dim3(128, 4), 256, 0, stream>>>(AOh, AOl, Wth, Wtl, bo, HS, out);
}

// Round 4
// 278.550 us; speedup vs baseline: 4.7482x; 1.1570x over previous
//
#include <hip/hip_runtime.h>

#define Tt 2048
#define Cc 512
#define Bb 4
#define BC (Bb * Cc)

typedef __attribute__((ext_vector_type(8))) short bf16x8;
typedef __attribute__((ext_vector_type(4))) float f32x4;

__device__ __forceinline__ short f2bf(float x) {
    union { float f; unsigned u; } v{x};
    unsigned r = v.u + 0x7FFF + ((v.u >> 16) & 1);
    return (short)(r >> 16);
}
__device__ __forceinline__ float bf2f(short h) {
    union { unsigned u; float f; } v{((unsigned)(unsigned short)h) << 16};
    return v.f;
}
__device__ __forceinline__ void split2(float x, short& h, short& l) {
    h = f2bf(x);
    l = f2bf(x - bf2f(h));
}

// ---------------------------------------------------------------------------
// Kernel 0: W[k][n] (x4) -> Wt[z][n][k] split hi/lo bf16.
// ---------------------------------------------------------------------------
__global__ __launch_bounds__(256) void wsetup(
    const float* __restrict__ Wq, const float* __restrict__ Wk,
    const float* __restrict__ Wv, const float* __restrict__ Wo,
    short* __restrict__ Wth, short* __restrict__ Wtl)
{
    const int z = blockIdx.y;
    const float* W = (z == 0) ? Wq : (z == 1) ? Wk : (z == 2) ? Wv : Wo;
    const int k0 = (blockIdx.x >> 3) * 64, n0 = (blockIdx.x & 7) * 64;
    const int tid = threadIdx.x;
    __shared__ float tile[64][65];

#pragma unroll
    for (int i = 0; i < 4; ++i) {
        const int idx = i * 256 + tid;
        const int kr = idx >> 4, c4 = idx & 15;
        float4 v = *(const float4*)&W[(size_t)(k0 + kr) * Cc + n0 + c4 * 4];
        tile[kr][c4 * 4 + 0] = v.x; tile[kr][c4 * 4 + 1] = v.y;
        tile[kr][c4 * 4 + 2] = v.z; tile[kr][c4 * 4 + 3] = v.w;
    }
    __syncthreads();
#pragma unroll
    for (int i = 0; i < 4; ++i) {
        const int idx = i * 256 + tid;
        const int nr = idx >> 4, k4 = idx & 15;
        short4 h, l;
        split2(tile[k4 * 4 + 0][nr], h.x, l.x);
        split2(tile[k4 * 4 + 1][nr], h.y, l.y);
        split2(tile[k4 * 4 + 2][nr], h.z, l.z);
        split2(tile[k4 * 4 + 3][nr], h.w, l.w);
        const size_t base = ((size_t)(z * 512 + n0 + nr)) * Cc + k0 + k4 * 4;
        *(short4*)&Wth[base] = h;
        *(short4*)&Wtl[base] = l;
    }
}

// ---------------------------------------------------------------------------
// Kernel 1: QKV GEMM, compensated split-bf16 MFMA. z==1 (K) stores raw hi/lo
// bf16 planes directly (ik factor folded into Q inside attn); z==0/2 fp32.
// ---------------------------------------------------------------------------
__global__ __launch_bounds__(256, 3) void qkv_mfma(
    const float* __restrict__ HS, const short* __restrict__ Wth,
    const short* __restrict__ Wtl,
    float* __restrict__ Q, short* __restrict__ Kh, short* __restrict__ Kl,
    float* __restrict__ V, float* __restrict__ colsum)
{
    const int mt = blockIdx.x;              // 64
    const int nt = blockIdx.y;              // 4
    const int z  = blockIdx.z;              // 3

    const int tid = threadIdx.x;
    const int wave = tid >> 6, lane = tid & 63;
    const int quad = lane >> 4, lm = lane & 15;
    const int wm = (wave & 1) * 64, wn = (wave >> 1) * 64;

    __shared__ short sAh[128 * 40], sAl[128 * 40];
    __shared__ short sBh[128 * 40], sBl[128 * 40];

    f32x4 acc[4][4];
#pragma unroll
    for (int mf = 0; mf < 4; ++mf)
#pragma unroll
        for (int nf = 0; nf < 4; ++nf) acc[mf][nf] = (f32x4){0.f, 0.f, 0.f, 0.f};

    const int r2 = tid >> 1, kc = (tid & 1) * 16;
    const float* ga  = HS + (size_t)(mt * 128 + r2) * Cc + kc;
    const short* gbh = Wth + ((size_t)(z * 512 + nt * 128 + r2)) * Cc + kc;
    const short* gbl = Wtl + ((size_t)(z * 512 + nt * 128 + r2)) * Cc + kc;

    for (int k0 = 0; k0 < Cc; k0 += 32) {
        __syncthreads();
#pragma unroll
        for (int j = 0; j < 4; ++j) {
            float4 a = *(const float4*)&ga[k0 + j * 4];
            short4 h, l;
            split2(a.x, h.x, l.x); split2(a.y, h.y, l.y);
            split2(a.z, h.z, l.z); split2(a.w, h.w, l.w);
            *(short4*)&sAh[r2 * 40 + kc + j * 4] = h;
            *(short4*)&sAl[r2 * 40 + kc + j * 4] = l;
        }
        {
            bf16x8 b0 = *(const bf16x8*)&gbh[k0];
            bf16x8 b1 = *(const bf16x8*)&gbh[k0 + 8];
            bf16x8 c0 = *(const bf16x8*)&gbl[k0];
            bf16x8 c1 = *(const bf16x8*)&gbl[k0 + 8];
            *(bf16x8*)&sBh[r2 * 40 + kc]     = b0;
            *(bf16x8*)&sBh[r2 * 40 + kc + 8] = b1;
            *(bf16x8*)&sBl[r2 * 40 + kc]     = c0;
            *(bf16x8*)&sBl[r2 * 40 + kc + 8] = c1;
        }
        __syncthreads();

        bf16x8 ah[4], al[4], bh[4], bl[4];
#pragma unroll
        for (int mf = 0; mf < 4; ++mf) {
            ah[mf] = *(const bf16x8*)&sAh[(wm + mf * 16 + lm) * 40 + quad * 8];
            al[mf] = *(const bf16x8*)&sAl[(wm + mf * 16 + lm) * 40 + quad * 8];
        }
#pragma unroll
        for (int nf = 0; nf < 4; ++nf) {
            bh[nf] = *(const bf16x8*)&sBh[(wn + nf * 16 + lm) * 40 + quad * 8];
            bl[nf] = *(const bf16x8*)&sBl[(wn + nf * 16 + lm) * 40 + quad * 8];
        }
#pragma unroll
        for (int mf = 0; mf < 4; ++mf)
#pragma unroll
            for (int nf = 0; nf < 4; ++nf) {
                acc[mf][nf] = __builtin_amdgcn_mfma_f32_16x16x32_bf16(ah[mf], bh[nf], acc[mf][nf], 0, 0, 0);
                acc[mf][nf] = __builtin_amdgcn_mfma_f32_16x16x32_bf16(ah[mf], bl[nf], acc[mf][nf], 0, 0, 0);
                acc[mf][nf] = __builtin_amdgcn_mfma_f32_16x16x32_bf16(al[mf], bh[nf], acc[mf][nf], 0, 0, 0);
            }
    }

    const int bidx = mt >> 4;
#pragma unroll
    for (int nf = 0; nf < 4; ++nf) {
        float cs = 0.f;
#pragma unroll
        for (int mf = 0; mf < 4; ++mf)
#pragma unroll
            for (int r = 0; r < 4; ++r) {
                const float v = acc[mf][nf][r];
                const size_t idx =
                    (size_t)(mt * 128 + wm + mf * 16 + quad * 4 + r) * Cc +
                    nt * 128 + wn + nf * 16 + lm;
                if (z == 1) {
                    short h, l;
                    split2(v, h, l);
                    Kh[idx] = h;
                    Kl[idx] = l;
                } else if (z == 0) {
                    Q[idx] = v;
                } else {
                    V[idx] = v;
                }
                cs += v * v;
            }
        cs += __shfl_xor(cs, 16, 64);
        cs += __shfl_xor(cs, 32, 64);
        if (lane < 16)
            atomicAdd(&colsum[(size_t)z * BC + bidx * Cc + nt * 128 + wn + nf * 16 + lane], cs);
    }
}

// ---------------------------------------------------------------------------
// Kernel 2: colsum -> 1/sqrt(mean + eps)
// ---------------------------------------------------------------------------
__global__ void inv_norm_kernel(const float* __restrict__ colsum,
                                float* __restrict__ inv)
{
    const int i = blockIdx.x * blockDim.x + threadIdx.x;
    if (i < 3 * BC) inv[i] = rsqrtf(colsum[i] * (1.0f / Tt) + 1e-4f);
}

// ---------------------------------------------------------------------------
// Kernel 3: V[b][t][c] -> VT[b][c][t] bf16, scaled by iv[b][c].
// ---------------------------------------------------------------------------
__global__ __launch_bounds__(256) void norm_vt(
    const float* __restrict__ V, const float* __restrict__ inv,
    short* __restrict__ VT)
{
    const int blk = blockIdx.x;
    const int b = blk >> 8, ct = (blk >> 5) & 7, tt = blk & 31;
    const int t0 = tt * 64, c0 = ct * 64;
    const int tid = threadIdx.x;

    __shared__ float tile[64][65];

#pragma unroll
    for (int i = 0; i < 4; ++i) {
        const int idx = i * 256 + tid;
        const int tr = idx >> 4, c4 = idx & 15;
        float4 v = *(const float4*)&V[(size_t)(b * Tt + t0 + tr) * Cc + c0 + c4 * 4];
        tile[tr][c4 * 4 + 0] = v.x; tile[tr][c4 * 4 + 1] = v.y;
        tile[tr][c4 * 4 + 2] = v.z; tile[tr][c4 * 4 + 3] = v.w;
    }
    __syncthreads();
#pragma unroll
    for (int i = 0; i < 4; ++i) {
        const int idx = i * 256 + tid;
        const int cr = idx >> 4, t4 = idx & 15;
        const float ivv = inv[2 * BC + b * Cc + c0 + cr];
        short4 o;
        o.x = f2bf(tile[t4 * 4 + 0][cr] * ivv);
        o.y = f2bf(tile[t4 * 4 + 1][cr] * ivv);
        o.z = f2bf(tile[t4 * 4 + 2][cr] * ivv);
        o.w = f2bf(tile[t4 * 4 + 3][cr] * ivv);
        *(short4*)&VT[(size_t)(b * Cc + c0 + cr) * Tt + t0 + t4 * 4] = o;
    }
}

// ---------------------------------------------------------------------------
// Kernel 4: MFMA flash attention v3.
//  - 4 waves x 32 Q-rows (2 m-frags) = 128 rows/block; grid (16, 32)
//  - K pre-split bf16 (raw); iq*ik*scale folded into Q fragments
//  - no-max softmax: p = exp(s), lane-local l partials, epilogue reduce
// ---------------------------------------------------------------------------
#define LSTR 72

__global__ __launch_bounds__(256, 2) void attn_mfma(
    const float* __restrict__ Q, const short* __restrict__ Kh,
    const short* __restrict__ Kl, const short* __restrict__ VT,
    const float* __restrict__ inv,
    short* __restrict__ AOh, short* __restrict__ AOl)
{
    const int qt = blockIdx.x;            // 16
    const int bh = blockIdx.y;            // 32
    const int b = bh >> 3, h = bh & 7;
    const int tid = threadIdx.x;
    const int wave = tid >> 6, lane = tid & 63;
    const int quad = lane >> 4, lm = lane & 15;

    __shared__ short sKh[64 * LSTR];
    __shared__ short sKl[64 * LSTR];
    __shared__ short sVT[64 * LSTR];
    __shared__ short sP[4 * 32 * LSTR];
    short* myP = sP + wave * 32 * LSTR;

    // ---- Q fragments: scaled by iq*ik*0.125, split hi/lo. 2 m-frags.
    bf16x8 qhi[2][2], qlo[2][2];
    {
        const float* iqp = inv + b * Cc + h * 64;
        const float* ikp = inv + BC + b * Cc + h * 64;
#pragma unroll
        for (int mf = 0; mf < 2; ++mf) {
            const int qrow = qt * 128 + wave * 32 + mf * 16 + lm;
            const float* qp = Q + (size_t)(b * Tt + qrow) * Cc + h * 64;
#pragma unroll
            for (int ks = 0; ks < 2; ++ks) {
                const int d0 = ks * 32 + quad * 8;
                float4 a  = *(const float4*)&qp[d0];
                float4 b4 = *(const float4*)&qp[d0 + 4];
                float4 ia = *(const float4*)&iqp[d0];
                float4 ib = *(const float4*)&iqp[d0 + 4];
                float4 ja = *(const float4*)&ikp[d0];
                float4 jb = *(const float4*)&ikp[d0 + 4];
                float vals[8] = {
                    a.x * ia.x * ja.x, a.y * ia.y * ja.y,
                    a.z * ia.z * ja.z, a.w * ia.w * ja.w,
                    b4.x * ib.x * jb.x, b4.y * ib.y * jb.y,
                    b4.z * ib.z * jb.z, b4.w * ib.w * jb.w };
#pragma unroll
                for (int j = 0; j < 8; ++j) {
                    float v = vals[j] * 0.125f;
                    short hi = f2bf(v);
                    qhi[mf][ks][j] = hi;
                    qlo[mf][ks][j] = f2bf(v - bf2f(hi));
                }
            }
        }
    }

    f32x4 o[2][4];
#pragma unroll
    for (int mf = 0; mf < 2; ++mf)
#pragma unroll
        for (int nt = 0; nt < 4; ++nt) o[mf][nt] = (f32x4){0.f, 0.f, 0.f, 0.f};
    float lsum[2][4] = {};

    for (int kt = 0; kt < 32; ++kt) {
        __syncthreads();
        // ---- stage K hi/lo + VT: straight bf16x8 copies
        {
            const size_t kbase = (size_t)(b * Tt + kt * 64) * Cc + h * 64;
            const size_t vbase = (size_t)(b * Cc + h * 64) * Tt + kt * 64;
#pragma unroll
            for (int i = 0; i < 2; ++i) {
                const int idx = i * 256 + tid;
                const int r = idx >> 3, c8 = (idx & 7) * 8;
                *(bf16x8*)&sKh[r * LSTR + c8] =
                    *(const bf16x8*)&Kh[kbase + (size_t)r * Cc + c8];
                *(bf16x8*)&sKl[r * LSTR + c8] =
                    *(const bf16x8*)&Kl[kbase + (size_t)r * Cc + c8];
                *(bf16x8*)&sVT[r * LSTR + c8] =
                    *(const bf16x8*)&VT[vbase + (size_t)r * Tt + c8];
            }
        }
        __syncthreads();

        // ---- S = Q K^T compensated
        f32x4 sacc[2][4];
#pragma unroll
        for (int mf = 0; mf < 2; ++mf)
#pragma unroll
            for (int nt = 0; nt < 4; ++nt) sacc[mf][nt] = (f32x4){0.f, 0.f, 0.f, 0.f};
#pragma unroll
        for (int nt = 0; nt < 4; ++nt) {
#pragma unroll
            for (int ks = 0; ks < 2; ++ks) {
                bf16x8 kh = *(const bf16x8*)&sKh[(16 * nt + lm) * LSTR + ks * 32 + quad * 8];
                bf16x8 kl = *(const bf16x8*)&sKl[(16 * nt + lm) * LSTR + ks * 32 + quad * 8];
#pragma unroll
                for (int mf = 0; mf < 2; ++mf) {
                    sacc[mf][nt] = __builtin_amdgcn_mfma_f32_16x16x32_bf16(qhi[mf][ks], kh, sacc[mf][nt], 0, 0, 0);
                    sacc[mf][nt] = __builtin_amdgcn_mfma_f32_16x16x32_bf16(qhi[mf][ks], kl, sacc[mf][nt], 0, 0, 0);
                    sacc[mf][nt] = __builtin_amdgcn_mfma_f32_16x16x32_bf16(qlo[mf][ks], kh, sacc[mf][nt], 0, 0, 0);
                }
            }
        }

        // ---- p = exp(s) (no max shift: cosine-attn scores are bounded),
        // lane-local l accumulation, P -> wave-private LDS (bf16, A-layout)
#pragma unroll
        for (int mf = 0; mf < 2; ++mf)
#pragma unroll
            for (int nt = 0; nt < 4; ++nt)
#pragma unroll
                for (int r = 0; r < 4; ++r) {
                    const float p = __expf(sacc[mf][nt][r]);
                    lsum[mf][r] += p;
                    myP[(mf * 16 + quad * 4 + r) * LSTR + nt * 16 + lm] = f2bf(p);
                }

        // ---- O += P V
#pragma unroll
        for (int ks = 0; ks < 2; ++ks) {
            bf16x8 vb[4];
#pragma unroll
            for (int nt = 0; nt < 4; ++nt)
                vb[nt] = *(const bf16x8*)&sVT[(16 * nt + lm) * LSTR + ks * 32 + quad * 8];
#pragma unroll
            for (int mf = 0; mf < 2; ++mf) {
                bf16x8 pa = *(const bf16x8*)&myP[(mf * 16 + lm) * LSTR + ks * 32 + quad * 8];
#pragma unroll
                for (int nt = 0; nt < 4; ++nt)
                    o[mf][nt] = __builtin_amdgcn_mfma_f32_16x16x32_bf16(pa, vb[nt], o[mf][nt], 0, 0, 0);
            }
        }
    }

    // ---- epilogue: reduce l over the 16 key-lanes, O /= l, write hi/lo bf16
#pragma unroll
    for (int mf = 0; mf < 2; ++mf)
#pragma unroll
        for (int r = 0; r < 4; ++r) {
            float s = lsum[mf][r];
            s += __shfl_xor(s, 1, 64);
            s += __shfl_xor(s, 2, 64);
            s += __shfl_xor(s, 4, 64);
            s += __shfl_xor(s, 8, 64);
            lsum[mf][r] = 1.0f / s;
        }
#pragma unroll
    for (int mf = 0; mf < 2; ++mf)
#pragma unroll
        for (int nt = 0; nt < 4; ++nt)
#pragma unroll
            for (int r = 0; r < 4; ++r) {
                const float v = o[mf][nt][r] * lsum[mf][r];
                const size_t idx =
                    (size_t)(b * Tt + qt * 128 + wave * 32 + mf * 16 + quad * 4 + r) * Cc +
                    h * 64 + nt * 16 + lm;
                short hi = f2bf(v);
                AOh[idx] = hi;
                AOl[idx] = f2bf(v - bf2f(hi));
            }
}

// ---------------------------------------------------------------------------
// Kernel 5: out = AO @ Wo + bo + residual, compensated MFMA.
// ---------------------------------------------------------------------------
__global__ __launch_bounds__(256, 2) void out_mfma(
    const short* __restrict__ AOh, const short* __restrict__ AOl,
    const short* __restrict__ Wth, const short* __restrict__ Wtl,
    const float* __restrict__ bo, const float* __restrict__ HS,
    float* __restrict__ Outp)
{
    const int mt = blockIdx.x;              // 128
    const int nt = blockIdx.y;              // 4
    const int tid = threadIdx.x;
    const int wave = tid >> 6, lane = tid & 63;
    const int quad = lane >> 4, lm = lane & 15;
    const int wm = (wave & 1) * 32, wn = (wave >> 1) * 64;

    __shared__ short sAh[64 * 40], sAl[64 * 40];
    __shared__ short sBh[128 * 40], sBl[128 * 40];

    f32x4 acc[2][4];
#pragma unroll
    for (int mf = 0; mf < 2; ++mf)
#pragma unroll
        for (int nf = 0; nf < 4; ++nf) acc[mf][nf] = (f32x4){0.f, 0.f, 0.f, 0.f};

    const int ra = tid >> 2, ka = (tid & 3) * 8;
    const int rb = tid >> 1, kb = (tid & 1) * 16;
    const short* gah = AOh + (size_t)(mt * 64 + ra) * Cc + ka;
    const short* gal = AOl + (size_t)(mt * 64 + ra) * Cc + ka;
    const short* gbh = Wth + ((size_t)(3 * 512 + nt * 128 + rb)) * Cc + kb;
    const short* gbl = Wtl + ((size_t)(3 * 512 + nt * 128 + rb)) * Cc + kb;

    for (int k0 = 0; k0 < Cc; k0 += 32) {
        __syncthreads();
        {
            bf16x8 a0 = *(const bf16x8*)&gah[k0];
            bf16x8 a1 = *(const bf16x8*)&gal[k0];
            *(bf16x8*)&sAh[ra * 40 + ka] = a0;
            *(bf16x8*)&sAl[ra * 40 + ka] = a1;
            bf16x8 b0 = *(const bf16x8*)&gbh[k0];
            bf16x8 b1 = *(const bf16x8*)&gbh[k0 + 8];
            bf16x8 c0 = *(const bf16x8*)&gbl[k0];
            bf16x8 c1 = *(const bf16x8*)&gbl[k0 + 8];
            *(bf16x8*)&sBh[rb * 40 + kb]     = b0;
            *(bf16x8*)&sBh[rb * 40 + kb + 8] = b1;
            *(bf16x8*)&sBl[rb * 40 + kb]     = c0;
            *(bf16x8*)&sBl[rb * 40 + kb + 8] = c1;
        }
        __syncthreads();

        bf16x8 ah[2], al[2], bh[4], bl[4];
#pragma unroll
        for (int mf = 0; mf < 2; ++mf) {
            ah[mf] = *(const bf16x8*)&sAh[(wm + mf * 16 + lm) * 40 + quad * 8];
            al[mf] = *(const bf16x8*)&sAl[(wm + mf * 16 + lm) * 40 + quad * 8];
        }
#pragma unroll
        for (int nf = 0; nf < 4; ++nf) {
            bh[nf] = *(const bf16x8*)&sBh[(wn + nf * 16 + lm) * 40 + quad * 8];
            bl[nf] = *(const bf16x8*)&sBl[(wn + nf * 16 + lm) * 40 + quad * 8];
        }
#pragma unroll
        for (int mf = 0; mf < 2; ++mf)
#pragma unroll
            for (int nf = 0; nf < 4; ++nf) {
                acc[mf][nf] = __builtin_amdgcn_mfma_f32_16x16x32_bf16(ah[mf], bh[nf], acc[mf][nf], 0, 0, 0);
                acc[mf][nf] = __builtin_amdgcn_mfma_f32_16x16x32_bf16(ah[mf], bl[nf], acc[mf][nf], 0, 0, 0);
                acc[mf][nf] = __builtin_amdgcn_mfma_f32_16x16x32_bf16(al[mf], bh[nf], acc[mf][nf], 0, 0, 0);
            }
    }

#pragma unroll
    for (int mf = 0; mf < 2; ++mf)
#pragma unroll
        for (int r = 0; r < 4; ++r) {
            const size_t m = (size_t)(mt * 64 + wm + mf * 16 + quad * 4 + r);
#pragma unroll
            for (int nf = 0; nf < 4; ++nf) {
                const int col = nt * 128 + wn + nf * 16 + lm;
                Outp[m * Cc + col] = acc[mf][nf][r] + bo[col] + HS[m * Cc + col];
            }
        }
}

// ---------------------------------------------------------------------------
extern "C" void kernel_launch(void* const* d_in, const int* in_sizes, int n_in,
                              void* d_out, int out_size, void* d_ws,
                              size_t ws_size, hipStream_t stream)
{
    const float* HS = (const float*)d_in[0];
    const float* Wq = (const float*)d_in[1];
    const float* Wk = (const float*)d_in[2];
    const float* Wv = (const float*)d_in[3];
    const float* Wo = (const float*)d_in[4];
    const float* bo = (const float*)d_in[5];
    float* out = (float*)d_out;

    float* ws = (float*)d_ws;
    const size_t SZ = (size_t)Bb * Tt * Cc;        // 4,194,304 floats
    float* Qb = ws;                                 // fp32
    short* Khb = (short*)(ws + SZ);                 // SZ shorts (in Kb region)
    short* Klb = Khb + SZ;                          // SZ shorts
    float* Vb = ws + 2 * SZ;                        // fp32; dead after norm_vt
    short* AOh = (short*)Vb;                        // aliases Vb
    short* AOl = AOh + SZ;
    short* VTh = (short*)(ws + 3 * SZ);             // SZ shorts
    short* Wth = (short*)(ws + 3 * SZ + SZ / 2);    // 4*512*512 shorts
    short* Wtl = Wth + 4 * Cc * Cc;
    float* colsum = ws + 3 * SZ + SZ / 2 + (4 * Cc * Cc);
    float* inv    = colsum + 3 * BC;

    hipMemsetAsync(colsum, 0, 3 * BC * sizeof(float), stream);

    wsetup<<<dim3(64, 4), 256, 0, stream>>>(Wq, Wk, Wv, Wo, Wth, Wtl);

    qkv_mfma<<<dim3(64, 4, 3), 256, 0, stream>>>(HS, Wth, Wtl, Qb, Khb, Klb, Vb, colsum);

    inv_norm_kernel<<<(3 * BC + 255) / 256, 256, 0, stream>>>(colsum, inv);

    norm_vt<<<1024, 256, 0, stream>>>(Vb, inv, VTh);

    attn_mfma<<<dim3(16, 32), 256, 0, stream>>>(Qb, Khb, Klb, VTh, inv, AOh, AOl);

    out_mfma<<<dim3(128, 4), 256, 0, stream>>>(AOh, AOl, Wth, Wtl, bo, HS, out);
}

// Round 5
// 203.798 us; speedup vs baseline: 6.4899x; 1.3668x over previous
//
#include <hip/hip_runtime.h>

#define Tt 2048
#define Cc 512
#define Bb 4
#define BC (Bb * Cc)

typedef __attribute__((ext_vector_type(8))) short bf16x8;
typedef __attribute__((ext_vector_type(4))) float f32x4;
typedef __attribute__((ext_vector_type(8))) _Float16 f16x8;
typedef __attribute__((ext_vector_type(4))) _Float16 f16x4;

__device__ __forceinline__ short f2bf(float x) {
    union { float f; unsigned u; } v{x};
    unsigned r = v.u + 0x7FFF + ((v.u >> 16) & 1);
    return (short)(r >> 16);
}
__device__ __forceinline__ float bf2f(short h) {
    union { unsigned u; float f; } v{((unsigned)(unsigned short)h) << 16};
    return v.f;
}
__device__ __forceinline__ void split2(float x, short& h, short& l) {
    h = f2bf(x);
    l = f2bf(x - bf2f(h));
}

// ---------------------------------------------------------------------------
// Kernel 0: W[k][n] (x4) -> Wt[z][n][k] split hi/lo bf16. (unchanged)
// ---------------------------------------------------------------------------
__global__ __launch_bounds__(256) void wsetup(
    const float* __restrict__ Wq, const float* __restrict__ Wk,
    const float* __restrict__ Wv, const float* __restrict__ Wo,
    short* __restrict__ Wth, short* __restrict__ Wtl)
{
    const int z = blockIdx.y;
    const float* W = (z == 0) ? Wq : (z == 1) ? Wk : (z == 2) ? Wv : Wo;
    const int k0 = (blockIdx.x >> 3) * 64, n0 = (blockIdx.x & 7) * 64;
    const int tid = threadIdx.x;
    __shared__ float tile[64][65];

#pragma unroll
    for (int i = 0; i < 4; ++i) {
        const int idx = i * 256 + tid;
        const int kr = idx >> 4, c4 = idx & 15;
        float4 v = *(const float4*)&W[(size_t)(k0 + kr) * Cc + n0 + c4 * 4];
        tile[kr][c4 * 4 + 0] = v.x; tile[kr][c4 * 4 + 1] = v.y;
        tile[kr][c4 * 4 + 2] = v.z; tile[kr][c4 * 4 + 3] = v.w;
    }
    __syncthreads();
#pragma unroll
    for (int i = 0; i < 4; ++i) {
        const int idx = i * 256 + tid;
        const int nr = idx >> 4, k4 = idx & 15;
        short4 h, l;
        split2(tile[k4 * 4 + 0][nr], h.x, l.x);
        split2(tile[k4 * 4 + 1][nr], h.y, l.y);
        split2(tile[k4 * 4 + 2][nr], h.z, l.z);
        split2(tile[k4 * 4 + 3][nr], h.w, l.w);
        const size_t base = ((size_t)(z * 512 + n0 + nr)) * Cc + k0 + k4 * 4;
        *(short4*)&Wth[base] = h;
        *(short4*)&Wtl[base] = l;
    }
}

// ---------------------------------------------------------------------------
// Kernel 1: QKV GEMM, compensated split-bf16 MFMA (unchanged math);
// epilogue stores Q/K/V as raw fp16 + column sum-of-squares (from fp32 acc).
// ---------------------------------------------------------------------------
__global__ __launch_bounds__(256, 3) void qkv_mfma(
    const float* __restrict__ HS, const short* __restrict__ Wth,
    const short* __restrict__ Wtl,
    _Float16* __restrict__ Qf, _Float16* __restrict__ Kf,
    _Float16* __restrict__ Vf, float* __restrict__ colsum)
{
    const int mt = blockIdx.x;              // 64
    const int nt = blockIdx.y;              // 4
    const int z  = blockIdx.z;              // 3
    _Float16* Out = (z == 0) ? Qf : (z == 1) ? Kf : Vf;

    const int tid = threadIdx.x;
    const int wave = tid >> 6, lane = tid & 63;
    const int quad = lane >> 4, lm = lane & 15;
    const int wm = (wave & 1) * 64, wn = (wave >> 1) * 64;

    __shared__ short sAh[128 * 40], sAl[128 * 40];
    __shared__ short sBh[128 * 40], sBl[128 * 40];

    f32x4 acc[4][4];
#pragma unroll
    for (int mf = 0; mf < 4; ++mf)
#pragma unroll
        for (int nf = 0; nf < 4; ++nf) acc[mf][nf] = (f32x4){0.f, 0.f, 0.f, 0.f};

    const int r2 = tid >> 1, kc = (tid & 1) * 16;
    const float* ga  = HS + (size_t)(mt * 128 + r2) * Cc + kc;
    const short* gbh = Wth + ((size_t)(z * 512 + nt * 128 + r2)) * Cc + kc;
    const short* gbl = Wtl + ((size_t)(z * 512 + nt * 128 + r2)) * Cc + kc;

    for (int k0 = 0; k0 < Cc; k0 += 32) {
        __syncthreads();
#pragma unroll
        for (int j = 0; j < 4; ++j) {
            float4 a = *(const float4*)&ga[k0 + j * 4];
            short4 h, l;
            split2(a.x, h.x, l.x); split2(a.y, h.y, l.y);
            split2(a.z, h.z, l.z); split2(a.w, h.w, l.w);
            *(short4*)&sAh[r2 * 40 + kc + j * 4] = h;
            *(short4*)&sAl[r2 * 40 + kc + j * 4] = l;
        }
        {
            bf16x8 b0 = *(const bf16x8*)&gbh[k0];
            bf16x8 b1 = *(const bf16x8*)&gbh[k0 + 8];
            bf16x8 c0 = *(const bf16x8*)&gbl[k0];
            bf16x8 c1 = *(const bf16x8*)&gbl[k0 + 8];
            *(bf16x8*)&sBh[r2 * 40 + kc]     = b0;
            *(bf16x8*)&sBh[r2 * 40 + kc + 8] = b1;
            *(bf16x8*)&sBl[r2 * 40 + kc]     = c0;
            *(bf16x8*)&sBl[r2 * 40 + kc + 8] = c1;
        }
        __syncthreads();

        bf16x8 ah[4], al[4], bh[4], bl[4];
#pragma unroll
        for (int mf = 0; mf < 4; ++mf) {
            ah[mf] = *(const bf16x8*)&sAh[(wm + mf * 16 + lm) * 40 + quad * 8];
            al[mf] = *(const bf16x8*)&sAl[(wm + mf * 16 + lm) * 40 + quad * 8];
        }
#pragma unroll
        for (int nf = 0; nf < 4; ++nf) {
            bh[nf] = *(const bf16x8*)&sBh[(wn + nf * 16 + lm) * 40 + quad * 8];
            bl[nf] = *(const bf16x8*)&sBl[(wn + nf * 16 + lm) * 40 + quad * 8];
        }
#pragma unroll
        for (int mf = 0; mf < 4; ++mf)
#pragma unroll
            for (int nf = 0; nf < 4; ++nf) {
                acc[mf][nf] = __builtin_amdgcn_mfma_f32_16x16x32_bf16(ah[mf], bh[nf], acc[mf][nf], 0, 0, 0);
                acc[mf][nf] = __builtin_amdgcn_mfma_f32_16x16x32_bf16(ah[mf], bl[nf], acc[mf][nf], 0, 0, 0);
                acc[mf][nf] = __builtin_amdgcn_mfma_f32_16x16x32_bf16(al[mf], bh[nf], acc[mf][nf], 0, 0, 0);
            }
    }

    const int bidx = mt >> 4;
#pragma unroll
    for (int nf = 0; nf < 4; ++nf) {
        float cs = 0.f;
#pragma unroll
        for (int mf = 0; mf < 4; ++mf)
#pragma unroll
            for (int r = 0; r < 4; ++r) {
                const float v = acc[mf][nf][r];
                const size_t idx =
                    (size_t)(mt * 128 + wm + mf * 16 + quad * 4 + r) * Cc +
                    nt * 128 + wn + nf * 16 + lm;
                Out[idx] = (_Float16)v;
                cs += v * v;
            }
        cs += __shfl_xor(cs, 16, 64);
        cs += __shfl_xor(cs, 32, 64);
        if (lane < 16)
            atomicAdd(&colsum[(size_t)z * BC + bidx * Cc + nt * 128 + wn + nf * 16 + lane], cs);
    }
}

// ---------------------------------------------------------------------------
// Kernel 2: colsum -> 1/sqrt(mean + eps)
// ---------------------------------------------------------------------------
__global__ void inv_norm_kernel(const float* __restrict__ colsum,
                                float* __restrict__ inv)
{
    const int i = blockIdx.x * blockDim.x + threadIdx.x;
    if (i < 3 * BC) inv[i] = rsqrtf(colsum[i] * (1.0f / Tt) + 1e-4f);
}

// ---------------------------------------------------------------------------
// Kernel 3: V[b][t][c] fp16 -> VT[b][c][t] fp16, scaled by iv[b][c].
// ---------------------------------------------------------------------------
__global__ __launch_bounds__(256) void norm_vt(
    const _Float16* __restrict__ V, const float* __restrict__ inv,
    _Float16* __restrict__ VT)
{
    const int blk = blockIdx.x;          // 4 * 8 * 32 = 1024
    const int b = blk >> 8, ct = (blk >> 5) & 7, tt = blk & 31;
    const int t0 = tt * 64, c0 = ct * 64;
    const int tid = threadIdx.x;

    __shared__ _Float16 tile[64 * 72];

#pragma unroll
    for (int i = 0; i < 2; ++i) {
        const int idx = i * 256 + tid;
        const int tr = idx >> 3, c8 = (idx & 7) * 8;
        *(f16x8*)&tile[tr * 72 + c8] =
            *(const f16x8*)&V[(size_t)(b * Tt + t0 + tr) * Cc + c0 + c8];
    }
    __syncthreads();
#pragma unroll
    for (int i = 0; i < 2; ++i) {
        const int idx = i * 256 + tid;
        const int cr = idx >> 3, t8 = (idx & 7) * 8;
        const float ivv = inv[2 * BC + b * Cc + c0 + cr];
        f16x8 o;
#pragma unroll
        for (int j = 0; j < 8; ++j)
            o[j] = (_Float16)((float)tile[(t8 + j) * 72 + cr] * ivv);
        *(f16x8*)&VT[(size_t)(b * Cc + c0 + cr) * Tt + t0 + t8] = o;
    }
}

// ---------------------------------------------------------------------------
// Kernel 4: fp16 MFMA flash attention, transposed (S^T / O^T) form.
//  - S^T = K Q^T: A=K (keys=m), B=Q (queries=n). C-layout: key=quad*4+r,
//    query=lm -> P rows (query-major) written as packed b64 fp16x4.
//  - O^T = VT P^T: A=VT (channels=m), B=P from LDS b128.
//  - no-max softmax (p=exp(s)); l per query via in-lane + quad shfl at end.
//  - register prefetch of next K/VT tile.
// ---------------------------------------------------------------------------
#define LSTR 72

__global__ __launch_bounds__(256, 2) void attn_mfma(
    const _Float16* __restrict__ Qf, const _Float16* __restrict__ Kf,
    const _Float16* __restrict__ VT, const float* __restrict__ inv,
    short* __restrict__ AOh, short* __restrict__ AOl)
{
    const int qt = blockIdx.x;            // 16
    const int bh = blockIdx.y;            // 32
    const int b = bh >> 3, h = bh & 7;
    const int tid = threadIdx.x;
    const int wave = tid >> 6, lane = tid & 63;
    const int quad = lane >> 4, lm = lane & 15;

    __shared__ _Float16 sK[64 * LSTR];
    __shared__ _Float16 sVT[64 * LSTR];
    __shared__ _Float16 sP[4 * 32 * LSTR];
    _Float16* myP = sP + wave * 32 * LSTR;

    // ---- Q fragments (B-operand layout: n=lm=query, k=quad*8+j), scaled by
    // iq*ik*0.125, fp16. 2 query-frags x 2 k-steps.
    f16x8 qb[2][2];
    {
        const float* iqp = inv + b * Cc + h * 64;
        const float* ikp = inv + BC + b * Cc + h * 64;
#pragma unroll
        for (int qf = 0; qf < 2; ++qf) {
            const int row = qt * 128 + wave * 32 + qf * 16 + lm;
#pragma unroll
            for (int ks = 0; ks < 2; ++ks) {
                const int d0 = ks * 32 + quad * 8;
                f16x8 qv = *(const f16x8*)&Qf[(size_t)(b * Tt + row) * Cc + h * 64 + d0];
#pragma unroll
                for (int j = 0; j < 8; ++j) {
                    const float f = (float)qv[j] * iqp[d0 + j] * ikp[d0 + j] * 0.125f;
                    qb[qf][ks][j] = (_Float16)f;
                }
            }
        }
    }

    f32x4 o[4][2];      // [cf][qf]: O^T frags, m=channel, n=query
#pragma unroll
    for (int cf = 0; cf < 4; ++cf)
#pragma unroll
        for (int qf = 0; qf < 2; ++qf) o[cf][qf] = (f32x4){0.f, 0.f, 0.f, 0.f};
    float ls[2] = {0.f, 0.f};

    // staging decode (2 chunks per thread per plane)
    const int sr0 = tid >> 3, sc0 = (tid & 7) * 8;          // chunk 0: rows 0..31
    const int sr1 = sr0 + 32;                               // chunk 1: rows 32..63
    const size_t kstr = (size_t)Cc, vstr = (size_t)Tt;
    const _Float16* gK = Kf + (size_t)b * Tt * Cc + h * 64;
    const _Float16* gV = VT + ((size_t)b * Cc + h * 64) * Tt;

    f16x8 rk0, rk1, rv0, rv1;
    {
        rk0 = *(const f16x8*)&gK[(size_t)(0 + sr0) * kstr + sc0];
        rk1 = *(const f16x8*)&gK[(size_t)(0 + sr1) * kstr + sc0];
        rv0 = *(const f16x8*)&gV[(size_t)sr0 * vstr + 0 + sc0];
        rv1 = *(const f16x8*)&gV[(size_t)sr1 * vstr + 0 + sc0];
    }

    for (int kt = 0; kt < 32; ++kt) {
        __syncthreads();
        *(f16x8*)&sK[sr0 * LSTR + sc0] = rk0;
        *(f16x8*)&sK[sr1 * LSTR + sc0] = rk1;
        *(f16x8*)&sVT[sr0 * LSTR + sc0] = rv0;
        *(f16x8*)&sVT[sr1 * LSTR + sc0] = rv1;
        __syncthreads();

        if (kt < 31) {
            const int t0 = (kt + 1) * 64;
            rk0 = *(const f16x8*)&gK[(size_t)(t0 + sr0) * kstr + sc0];
            rk1 = *(const f16x8*)&gK[(size_t)(t0 + sr1) * kstr + sc0];
            rv0 = *(const f16x8*)&gV[(size_t)sr0 * vstr + t0 + sc0];
            rv1 = *(const f16x8*)&gV[(size_t)sr1 * vstr + t0 + sc0];
        }

        // ---- S^T = K Q^T
        f32x4 st[4][2];
#pragma unroll
        for (int kf = 0; kf < 4; ++kf)
#pragma unroll
            for (int qf = 0; qf < 2; ++qf) st[kf][qf] = (f32x4){0.f, 0.f, 0.f, 0.f};
#pragma unroll
        for (int ks = 0; ks < 2; ++ks) {
            f16x8 ka[4];
#pragma unroll
            for (int kf = 0; kf < 4; ++kf)
                ka[kf] = *(const f16x8*)&sK[(kf * 16 + lm) * LSTR + ks * 32 + quad * 8];
#pragma unroll
            for (int kf = 0; kf < 4; ++kf)
#pragma unroll
                for (int qf = 0; qf < 2; ++qf)
                    st[kf][qf] = __builtin_amdgcn_mfma_f32_16x16x32_f16(ka[kf], qb[qf][ks], st[kf][qf], 0, 0, 0);
        }

        // ---- p = exp(s); P (query-major rows) packed b64 writes; l partials
#pragma unroll
        for (int kf = 0; kf < 4; ++kf)
#pragma unroll
            for (int qf = 0; qf < 2; ++qf) {
                f16x4 pk;
#pragma unroll
                for (int r = 0; r < 4; ++r) {
                    const float p = __expf(st[kf][qf][r]);
                    ls[qf] += p;
                    pk[r] = (_Float16)p;
                }
                *(f16x4*)&myP[(qf * 16 + lm) * LSTR + kf * 16 + quad * 4] = pk;
            }

        // ---- O^T += VT P^T
#pragma unroll
        for (int ks = 0; ks < 2; ++ks) {
            f16x8 pb[2];
#pragma unroll
            for (int qf = 0; qf < 2; ++qf)
                pb[qf] = *(const f16x8*)&myP[(qf * 16 + lm) * LSTR + ks * 32 + quad * 8];
            f16x8 va[4];
#pragma unroll
            for (int cf = 0; cf < 4; ++cf)
                va[cf] = *(const f16x8*)&sVT[(cf * 16 + lm) * LSTR + ks * 32 + quad * 8];
#pragma unroll
            for (int cf = 0; cf < 4; ++cf)
#pragma unroll
                for (int qf = 0; qf < 2; ++qf)
                    o[cf][qf] = __builtin_amdgcn_mfma_f32_16x16x32_f16(va[cf], pb[qf], o[cf][qf], 0, 0, 0);
        }
    }

    // ---- epilogue: l reduce over quads, O^T /= l, vectorized bf16 hi/lo out
    float il[2];
#pragma unroll
    for (int qf = 0; qf < 2; ++qf) {
        float s = ls[qf];
        s += __shfl_xor(s, 16, 64);
        s += __shfl_xor(s, 32, 64);
        il[qf] = 1.0f / s;
    }
#pragma unroll
    for (int qf = 0; qf < 2; ++qf) {
        const size_t row = (size_t)(b * Tt + qt * 128 + wave * 32 + qf * 16 + lm);
#pragma unroll
        for (int cf = 0; cf < 4; ++cf) {
            const int col = h * 64 + cf * 16 + quad * 4;
            short4 hh, ll;
            float v0 = o[cf][qf][0] * il[qf];
            float v1 = o[cf][qf][1] * il[qf];
            float v2 = o[cf][qf][2] * il[qf];
            float v3 = o[cf][qf][3] * il[qf];
            split2(v0, hh.x, ll.x); split2(v1, hh.y, ll.y);
            split2(v2, hh.z, ll.z); split2(v3, hh.w, ll.w);
            *(short4*)&AOh[row * Cc + col] = hh;
            *(short4*)&AOl[row * Cc + col] = ll;
        }
    }
}

// ---------------------------------------------------------------------------
// Kernel 5: out = AO @ Wo + bo + residual, compensated MFMA. (unchanged)
// ---------------------------------------------------------------------------
__global__ __launch_bounds__(256, 2) void out_mfma(
    const short* __restrict__ AOh, const short* __restrict__ AOl,
    const short* __restrict__ Wth, const short* __restrict__ Wtl,
    const float* __restrict__ bo, const float* __restrict__ HS,
    float* __restrict__ Outp)
{
    const int mt = blockIdx.x;              // 128
    const int nt = blockIdx.y;              // 4
    const int tid = threadIdx.x;
    const int wave = tid >> 6, lane = tid & 63;
    const int quad = lane >> 4, lm = lane & 15;
    const int wm = (wave & 1) * 32, wn = (wave >> 1) * 64;

    __shared__ short sAh[64 * 40], sAl[64 * 40];
    __shared__ short sBh[128 * 40], sBl[128 * 40];

    f32x4 acc[2][4];
#pragma unroll
    for (int mf = 0; mf < 2; ++mf)
#pragma unroll
        for (int nf = 0; nf < 4; ++nf) acc[mf][nf] = (f32x4){0.f, 0.f, 0.f, 0.f};

    const int ra = tid >> 2, ka = (tid & 3) * 8;
    const int rb = tid >> 1, kb = (tid & 1) * 16;
    const short* gah = AOh + (size_t)(mt * 64 + ra) * Cc + ka;
    const short* gal = AOl + (size_t)(mt * 64 + ra) * Cc + ka;
    const short* gbh = Wth + ((size_t)(3 * 512 + nt * 128 + rb)) * Cc + kb;
    const short* gbl = Wtl + ((size_t)(3 * 512 + nt * 128 + rb)) * Cc + kb;

    for (int k0 = 0; k0 < Cc; k0 += 32) {
        __syncthreads();
        {
            bf16x8 a0 = *(const bf16x8*)&gah[k0];
            bf16x8 a1 = *(const bf16x8*)&gal[k0];
            *(bf16x8*)&sAh[ra * 40 + ka] = a0;
            *(bf16x8*)&sAl[ra * 40 + ka] = a1;
            bf16x8 b0 = *(const bf16x8*)&gbh[k0];
            bf16x8 b1 = *(const bf16x8*)&gbh[k0 + 8];
            bf16x8 c0 = *(const bf16x8*)&gbl[k0];
            bf16x8 c1 = *(const bf16x8*)&gbl[k0 + 8];
            *(bf16x8*)&sBh[rb * 40 + kb]     = b0;
            *(bf16x8*)&sBh[rb * 40 + kb + 8] = b1;
            *(bf16x8*)&sBl[rb * 40 + kb]     = c0;
            *(bf16x8*)&sBl[rb * 40 + kb + 8] = c1;
        }
        __syncthreads();

        bf16x8 ah[2], al[2], bh[4], bl[4];
#pragma unroll
        for (int mf = 0; mf < 2; ++mf) {
            ah[mf] = *(const bf16x8*)&sAh[(wm + mf * 16 + lm) * 40 + quad * 8];
            al[mf] = *(const bf16x8*)&sAl[(wm + mf * 16 + lm) * 40 + quad * 8];
        }
#pragma unroll
        for (int nf = 0; nf < 4; ++nf) {
            bh[nf] = *(const bf16x8*)&sBh[(wn + nf * 16 + lm) * 40 + quad * 8];
            bl[nf] = *(const bf16x8*)&sBl[(wn + nf * 16 + lm) * 40 + quad * 8];
        }
#pragma unroll
        for (int mf = 0; mf < 2; ++mf)
#pragma unroll
            for (int nf = 0; nf < 4; ++nf) {
                acc[mf][nf] = __builtin_amdgcn_mfma_f32_16x16x32_bf16(ah[mf], bh[nf], acc[mf][nf], 0, 0, 0);
                acc[mf][nf] = __builtin_amdgcn_mfma_f32_16x16x32_bf16(ah[mf], bl[nf], acc[mf][nf], 0, 0, 0);
                acc[mf][nf] = __builtin_amdgcn_mfma_f32_16x16x32_bf16(al[mf], bh[nf], acc[mf][nf], 0, 0, 0);
            }
    }

#pragma unroll
    for (int mf = 0; mf < 2; ++mf)
#pragma unroll
        for (int r = 0; r < 4; ++r) {
            const size_t m = (size_t)(mt * 64 + wm + mf * 16 + quad * 4 + r);
#pragma unroll
            for (int nf = 0; nf < 4; ++nf) {
                const int col = nt * 128 + wn + nf * 16 + lm;
                Outp[m * Cc + col] = acc[mf][nf][r] + bo[col] + HS[m * Cc + col];
            }
        }
}

// ---------------------------------------------------------------------------
extern "C" void kernel_launch(void* const* d_in, const int* in_sizes, int n_in,
                              void* d_out, int out_size, void* d_ws,
                              size_t ws_size, hipStream_t stream)
{
    const float* HS = (const float*)d_in[0];
    const float* Wq = (const float*)d_in[1];
    const float* Wk = (const float*)d_in[2];
    const float* Wv = (const float*)d_in[3];
    const float* Wo = (const float*)d_in[4];
    const float* bo = (const float*)d_in[5];
    float* out = (float*)d_out;

    float* ws = (float*)d_ws;
    const size_t SZ = (size_t)Bb * Tt * Cc;        // 4,194,304 elements
    // all fp16/short regions are SZ elements = SZ/2 floats
    _Float16* Qf = (_Float16*)ws;                   // [0, 0.5SZ)
    _Float16* Kf = (_Float16*)(ws + SZ / 2);        // [0.5, 1.0)
    _Float16* Vf = (_Float16*)(ws + SZ);            // [1.0, 1.5) dead after norm_vt
    _Float16* VTh = (_Float16*)(ws + 3 * SZ / 2);   // [1.5, 2.0)
    short* AOh = (short*)(ws + 2 * SZ);             // [2.0, 2.5)
    short* AOl = (short*)(ws + 5 * SZ / 2);         // [2.5, 3.0)
    short* Wth = (short*)(ws + 3 * SZ);             // 4*512*512 shorts = 512K floats
    short* Wtl = Wth + 4 * Cc * Cc;
    float* colsum = ws + 3 * SZ + (4 * Cc * Cc);    // (two short planes = 1M floats)
    float* inv    = colsum + 3 * BC;

    hipMemsetAsync(colsum, 0, 3 * BC * sizeof(float), stream);

    wsetup<<<dim3(64, 4), 256, 0, stream>>>(Wq, Wk, Wv, Wo, Wth, Wtl);

    qkv_mfma<<<dim3(64, 4, 3), 256, 0, stream>>>(HS, Wth, Wtl, Qf, Kf, Vf, colsum);

    inv_norm_kernel<<<(3 * BC + 255) / 256, 256, 0, stream>>>(colsum, inv);

    norm_vt<<<1024, 256, 0, stream>>>(Vf, inv, VTh);

    attn_mfma<<<dim3(16, 32), 256, 0, stream>>>(Qf, Kf, VTh, inv, AOh, AOl);

    out_mfma<<<dim3(128, 4), 256, 0, stream>>>(AOh, AOl, Wth, Wtl, bo, HS, out);
}

// Round 6
// 184.991 us; speedup vs baseline: 7.1497x; 1.1017x over previous
//
#include <hip/hip_runtime.h>

#define Tt 2048
#define Cc 512
#define Bb 4
#define BC (Bb * Cc)

typedef __attribute__((ext_vector_type(4))) float f32x4;
typedef __attribute__((ext_vector_type(8))) _Float16 f16x8;
typedef __attribute__((ext_vector_type(4))) _Float16 f16x4;

// ---------------------------------------------------------------------------
// Kernel 0: W[k][n] (x4) -> Wt[z][n][k] fp16 (single plane).
// ---------------------------------------------------------------------------
__global__ __launch_bounds__(256) void wsetup(
    const float* __restrict__ Wq, const float* __restrict__ Wk,
    const float* __restrict__ Wv, const float* __restrict__ Wo,
    _Float16* __restrict__ Wt)
{
    const int z = blockIdx.y;
    const float* W = (z == 0) ? Wq : (z == 1) ? Wk : (z == 2) ? Wv : Wo;
    const int k0 = (blockIdx.x >> 3) * 64, n0 = (blockIdx.x & 7) * 64;
    const int tid = threadIdx.x;
    __shared__ float tile[64][65];

#pragma unroll
    for (int i = 0; i < 4; ++i) {
        const int idx = i * 256 + tid;
        const int kr = idx >> 4, c4 = idx & 15;
        float4 v = *(const float4*)&W[(size_t)(k0 + kr) * Cc + n0 + c4 * 4];
        tile[kr][c4 * 4 + 0] = v.x; tile[kr][c4 * 4 + 1] = v.y;
        tile[kr][c4 * 4 + 2] = v.z; tile[kr][c4 * 4 + 3] = v.w;
    }
    __syncthreads();
#pragma unroll
    for (int i = 0; i < 4; ++i) {
        const int idx = i * 256 + tid;
        const int nr = idx >> 4, k4 = idx & 15;
        f16x4 o;
        o[0] = (_Float16)tile[k4 * 4 + 0][nr];
        o[1] = (_Float16)tile[k4 * 4 + 1][nr];
        o[2] = (_Float16)tile[k4 * 4 + 2][nr];
        o[3] = (_Float16)tile[k4 * 4 + 3][nr];
        *(f16x4*)&Wt[((size_t)(z * 512 + n0 + nr)) * Cc + k0 + k4 * 4] = o;
    }
}

// ---------------------------------------------------------------------------
// Kernel 1: QKV GEMM, single-term fp16 MFMA. 128x128 tile, 4 waves, BK=32.
// Epilogue: fp16 store + per-(b,channel) column sum-of-squares (fp32 acc).
// ---------------------------------------------------------------------------
__global__ __launch_bounds__(256, 3) void qkv_mfma(
    const float* __restrict__ HS, const _Float16* __restrict__ Wt,
    _Float16* __restrict__ Qf, _Float16* __restrict__ Kf,
    _Float16* __restrict__ Vf, float* __restrict__ colsum)
{
    const int mt = blockIdx.x;              // 64
    const int nt = blockIdx.y;              // 4
    const int z  = blockIdx.z;              // 3
    _Float16* Out = (z == 0) ? Qf : (z == 1) ? Kf : Vf;

    const int tid = threadIdx.x;
    const int wave = tid >> 6, lane = tid & 63;
    const int quad = lane >> 4, lm = lane & 15;
    const int wm = (wave & 1) * 64, wn = (wave >> 1) * 64;

    __shared__ _Float16 sA[128 * 40];
    __shared__ _Float16 sB[128 * 40];

    f32x4 acc[4][4];
#pragma unroll
    for (int mf = 0; mf < 4; ++mf)
#pragma unroll
        for (int nf = 0; nf < 4; ++nf) acc[mf][nf] = (f32x4){0.f, 0.f, 0.f, 0.f};

    const int r2 = tid >> 1, kc = (tid & 1) * 16;
    const float* ga = HS + (size_t)(mt * 128 + r2) * Cc + kc;
    const _Float16* gb = Wt + ((size_t)(z * 512 + nt * 128 + r2)) * Cc + kc;

    for (int k0 = 0; k0 < Cc; k0 += 32) {
        __syncthreads();
        {
            float4 a0 = *(const float4*)&ga[k0];
            float4 a1 = *(const float4*)&ga[k0 + 4];
            float4 a2 = *(const float4*)&ga[k0 + 8];
            float4 a3 = *(const float4*)&ga[k0 + 12];
            f16x8 h0, h1;
            h0[0] = (_Float16)a0.x; h0[1] = (_Float16)a0.y;
            h0[2] = (_Float16)a0.z; h0[3] = (_Float16)a0.w;
            h0[4] = (_Float16)a1.x; h0[5] = (_Float16)a1.y;
            h0[6] = (_Float16)a1.z; h0[7] = (_Float16)a1.w;
            h1[0] = (_Float16)a2.x; h1[1] = (_Float16)a2.y;
            h1[2] = (_Float16)a2.z; h1[3] = (_Float16)a2.w;
            h1[4] = (_Float16)a3.x; h1[5] = (_Float16)a3.y;
            h1[6] = (_Float16)a3.z; h1[7] = (_Float16)a3.w;
            *(f16x8*)&sA[r2 * 40 + kc]     = h0;
            *(f16x8*)&sA[r2 * 40 + kc + 8] = h1;
            *(f16x8*)&sB[r2 * 40 + kc]     = *(const f16x8*)&gb[k0];
            *(f16x8*)&sB[r2 * 40 + kc + 8] = *(const f16x8*)&gb[k0 + 8];
        }
        __syncthreads();

        f16x8 ah[4], bh[4];
#pragma unroll
        for (int mf = 0; mf < 4; ++mf)
            ah[mf] = *(const f16x8*)&sA[(wm + mf * 16 + lm) * 40 + quad * 8];
#pragma unroll
        for (int nf = 0; nf < 4; ++nf)
            bh[nf] = *(const f16x8*)&sB[(wn + nf * 16 + lm) * 40 + quad * 8];
#pragma unroll
        for (int mf = 0; mf < 4; ++mf)
#pragma unroll
            for (int nf = 0; nf < 4; ++nf)
                acc[mf][nf] = __builtin_amdgcn_mfma_f32_16x16x32_f16(ah[mf], bh[nf], acc[mf][nf], 0, 0, 0);
    }

    const int bidx = mt >> 4;
#pragma unroll
    for (int nf = 0; nf < 4; ++nf) {
        float cs = 0.f;
#pragma unroll
        for (int mf = 0; mf < 4; ++mf)
#pragma unroll
            for (int r = 0; r < 4; ++r) {
                const float v = acc[mf][nf][r];
                const size_t idx =
                    (size_t)(mt * 128 + wm + mf * 16 + quad * 4 + r) * Cc +
                    nt * 128 + wn + nf * 16 + lm;
                Out[idx] = (_Float16)v;
                cs += v * v;
            }
        cs += __shfl_xor(cs, 16, 64);
        cs += __shfl_xor(cs, 32, 64);
        if (lane < 16)
            atomicAdd(&colsum[(size_t)z * BC + bidx * Cc + nt * 128 + wn + nf * 16 + lane], cs);
    }
}

// ---------------------------------------------------------------------------
// Kernel 2: colsum -> 1/sqrt(mean + eps)
// ---------------------------------------------------------------------------
__global__ void inv_norm_kernel(const float* __restrict__ colsum,
                                float* __restrict__ inv)
{
    const int i = blockIdx.x * blockDim.x + threadIdx.x;
    if (i < 3 * BC) inv[i] = rsqrtf(colsum[i] * (1.0f / Tt) + 1e-4f);
}

// ---------------------------------------------------------------------------
// Kernel 3: V[b][t][c] fp16 -> VT[b][c][t] fp16 (pure transpose; iv folded
// into attn epilogue).
// ---------------------------------------------------------------------------
__global__ __launch_bounds__(256) void norm_vt(
    const _Float16* __restrict__ V, _Float16* __restrict__ VT)
{
    const int blk = blockIdx.x;          // 4 * 8 * 32 = 1024
    const int b = blk >> 8, ct = (blk >> 5) & 7, tt = blk & 31;
    const int t0 = tt * 64, c0 = ct * 64;
    const int tid = threadIdx.x;

    __shared__ _Float16 tile[64 * 72];

#pragma unroll
    for (int i = 0; i < 2; ++i) {
        const int idx = i * 256 + tid;
        const int tr = idx >> 3, c8 = (idx & 7) * 8;
        *(f16x8*)&tile[tr * 72 + c8] =
            *(const f16x8*)&V[(size_t)(b * Tt + t0 + tr) * Cc + c0 + c8];
    }
    __syncthreads();
#pragma unroll
    for (int i = 0; i < 2; ++i) {
        const int idx = i * 256 + tid;
        const int cr = idx >> 3, t8 = (idx & 7) * 8;
        f16x8 o;
#pragma unroll
        for (int j = 0; j < 8; ++j) o[j] = tile[(t8 + j) * 72 + cr];
        *(f16x8*)&VT[(size_t)(b * Cc + c0 + cr) * Tt + t0 + t8] = o;
    }
}

// ---------------------------------------------------------------------------
// Kernel 4: fp16 MFMA flash attention, transposed (S^T / O^T) form.
// iq*ik*scale folded into Q frags; iv folded into epilogue; AO fp16 single.
// ---------------------------------------------------------------------------
#define LSTR 72

__global__ __launch_bounds__(256, 2) void attn_mfma(
    const _Float16* __restrict__ Qf, const _Float16* __restrict__ Kf,
    const _Float16* __restrict__ VT, const float* __restrict__ inv,
    _Float16* __restrict__ AO)
{
    const int qt = blockIdx.x;            // 16
    const int bh = blockIdx.y;            // 32
    const int b = bh >> 3, h = bh & 7;
    const int tid = threadIdx.x;
    const int wave = tid >> 6, lane = tid & 63;
    const int quad = lane >> 4, lm = lane & 15;

    __shared__ _Float16 sK[64 * LSTR];
    __shared__ _Float16 sVT[64 * LSTR];
    __shared__ _Float16 sP[4 * 32 * LSTR];
    _Float16* myP = sP + wave * 32 * LSTR;

    // ---- Q fragments (B-operand: n=lm=query, k=quad*8+j), iq*ik*0.125 folded
    f16x8 qb[2][2];
    {
        const float* iqp = inv + b * Cc + h * 64;
        const float* ikp = inv + BC + b * Cc + h * 64;
#pragma unroll
        for (int qf = 0; qf < 2; ++qf) {
            const int row = qt * 128 + wave * 32 + qf * 16 + lm;
#pragma unroll
            for (int ks = 0; ks < 2; ++ks) {
                const int d0 = ks * 32 + quad * 8;
                f16x8 qv = *(const f16x8*)&Qf[(size_t)(b * Tt + row) * Cc + h * 64 + d0];
#pragma unroll
                for (int j = 0; j < 8; ++j) {
                    const float f = (float)qv[j] * iqp[d0 + j] * ikp[d0 + j] * 0.125f;
                    qb[qf][ks][j] = (_Float16)f;
                }
            }
        }
    }

    f32x4 o[4][2];      // [cf][qf]: O^T frags, m=channel, n=query
#pragma unroll
    for (int cf = 0; cf < 4; ++cf)
#pragma unroll
        for (int qf = 0; qf < 2; ++qf) o[cf][qf] = (f32x4){0.f, 0.f, 0.f, 0.f};
    float ls[2] = {0.f, 0.f};

    const int sr0 = tid >> 3, sc0 = (tid & 7) * 8;
    const int sr1 = sr0 + 32;
    const _Float16* gK = Kf + (size_t)b * Tt * Cc + h * 64;
    const _Float16* gV = VT + ((size_t)b * Cc + h * 64) * Tt;

    f16x8 rk0, rk1, rv0, rv1;
    {
        rk0 = *(const f16x8*)&gK[(size_t)sr0 * Cc + sc0];
        rk1 = *(const f16x8*)&gK[(size_t)sr1 * Cc + sc0];
        rv0 = *(const f16x8*)&gV[(size_t)sr0 * Tt + sc0];
        rv1 = *(const f16x8*)&gV[(size_t)sr1 * Tt + sc0];
    }

    for (int kt = 0; kt < 32; ++kt) {
        __syncthreads();
        *(f16x8*)&sK[sr0 * LSTR + sc0] = rk0;
        *(f16x8*)&sK[sr1 * LSTR + sc0] = rk1;
        *(f16x8*)&sVT[sr0 * LSTR + sc0] = rv0;
        *(f16x8*)&sVT[sr1 * LSTR + sc0] = rv1;
        __syncthreads();

        if (kt < 31) {
            const int t0 = (kt + 1) * 64;
            rk0 = *(const f16x8*)&gK[(size_t)(t0 + sr0) * Cc + sc0];
            rk1 = *(const f16x8*)&gK[(size_t)(t0 + sr1) * Cc + sc0];
            rv0 = *(const f16x8*)&gV[(size_t)sr0 * Tt + t0 + sc0];
            rv1 = *(const f16x8*)&gV[(size_t)sr1 * Tt + t0 + sc0];
        }

        // ---- S^T = K Q^T
        f32x4 st[4][2];
#pragma unroll
        for (int kf = 0; kf < 4; ++kf)
#pragma unroll
            for (int qf = 0; qf < 2; ++qf) st[kf][qf] = (f32x4){0.f, 0.f, 0.f, 0.f};
#pragma unroll
        for (int ks = 0; ks < 2; ++ks) {
            f16x8 ka[4];
#pragma unroll
            for (int kf = 0; kf < 4; ++kf)
                ka[kf] = *(const f16x8*)&sK[(kf * 16 + lm) * LSTR + ks * 32 + quad * 8];
#pragma unroll
            for (int kf = 0; kf < 4; ++kf)
#pragma unroll
                for (int qf = 0; qf < 2; ++qf)
                    st[kf][qf] = __builtin_amdgcn_mfma_f32_16x16x32_f16(ka[kf], qb[qf][ks], st[kf][qf], 0, 0, 0);
        }

        // ---- p = exp(s); P rows packed b64; l partials
#pragma unroll
        for (int kf = 0; kf < 4; ++kf)
#pragma unroll
            for (int qf = 0; qf < 2; ++qf) {
                f16x4 pk;
#pragma unroll
                for (int r = 0; r < 4; ++r) {
                    const float p = __expf(st[kf][qf][r]);
                    ls[qf] += p;
                    pk[r] = (_Float16)p;
                }
                *(f16x4*)&myP[(qf * 16 + lm) * LSTR + kf * 16 + quad * 4] = pk;
            }

        // ---- O^T += VT P^T
#pragma unroll
        for (int ks = 0; ks < 2; ++ks) {
            f16x8 pb[2];
#pragma unroll
            for (int qf = 0; qf < 2; ++qf)
                pb[qf] = *(const f16x8*)&myP[(qf * 16 + lm) * LSTR + ks * 32 + quad * 8];
            f16x8 va[4];
#pragma unroll
            for (int cf = 0; cf < 4; ++cf)
                va[cf] = *(const f16x8*)&sVT[(cf * 16 + lm) * LSTR + ks * 32 + quad * 8];
#pragma unroll
            for (int cf = 0; cf < 4; ++cf)
#pragma unroll
                for (int qf = 0; qf < 2; ++qf)
                    o[cf][qf] = __builtin_amdgcn_mfma_f32_16x16x32_f16(va[cf], pb[qf], o[cf][qf], 0, 0, 0);
        }
    }

    // ---- epilogue: l reduce over quads, O /= l, * iv (per-channel), fp16 out
    float il[2];
#pragma unroll
    for (int qf = 0; qf < 2; ++qf) {
        float s = ls[qf];
        s += __shfl_xor(s, 16, 64);
        s += __shfl_xor(s, 32, 64);
        il[qf] = 1.0f / s;
    }
    const float* ivp = inv + 2 * BC + b * Cc + h * 64;
    float iv[4][4];
#pragma unroll
    for (int cf = 0; cf < 4; ++cf) {
        float4 t = *(const float4*)&ivp[cf * 16 + quad * 4];
        iv[cf][0] = t.x; iv[cf][1] = t.y; iv[cf][2] = t.z; iv[cf][3] = t.w;
    }
#pragma unroll
    for (int qf = 0; qf < 2; ++qf) {
        const size_t row = (size_t)(b * Tt + qt * 128 + wave * 32 + qf * 16 + lm);
#pragma unroll
        for (int cf = 0; cf < 4; ++cf) {
            f16x4 pk;
#pragma unroll
            for (int r = 0; r < 4; ++r)
                pk[r] = (_Float16)(o[cf][qf][r] * il[qf] * iv[cf][r]);
            *(f16x4*)&AO[row * Cc + h * 64 + cf * 16 + quad * 4] = pk;
        }
    }
}

// ---------------------------------------------------------------------------
// Kernel 5: out = AO @ Wo + bo + residual, single-term fp16 MFMA.
// 64x128 tile, 4 waves (each 32x64).
// ---------------------------------------------------------------------------
__global__ __launch_bounds__(256, 2) void out_mfma(
    const _Float16* __restrict__ AO, const _Float16* __restrict__ Wt,
    const float* __restrict__ bo, const float* __restrict__ HS,
    float* __restrict__ Outp)
{
    const int mt = blockIdx.x;              // 128
    const int nt = blockIdx.y;              // 4
    const int tid = threadIdx.x;
    const int wave = tid >> 6, lane = tid & 63;
    const int quad = lane >> 4, lm = lane & 15;
    const int wm = (wave & 1) * 32, wn = (wave >> 1) * 64;

    __shared__ _Float16 sA[64 * 40];
    __shared__ _Float16 sB[128 * 40];

    f32x4 acc[2][4];
#pragma unroll
    for (int mf = 0; mf < 2; ++mf)
#pragma unroll
        for (int nf = 0; nf < 4; ++nf) acc[mf][nf] = (f32x4){0.f, 0.f, 0.f, 0.f};

    const int ra = tid >> 2, ka = (tid & 3) * 8;
    const int rb = tid >> 1, kb = (tid & 1) * 16;
    const _Float16* gah = AO + (size_t)(mt * 64 + ra) * Cc + ka;
    const _Float16* gbh = Wt + ((size_t)(3 * 512 + nt * 128 + rb)) * Cc + kb;

    for (int k0 = 0; k0 < Cc; k0 += 32) {
        __syncthreads();
        {
            *(f16x8*)&sA[ra * 40 + ka] = *(const f16x8*)&gah[k0];
            *(f16x8*)&sB[rb * 40 + kb]     = *(const f16x8*)&gbh[k0];
            *(f16x8*)&sB[rb * 40 + kb + 8] = *(const f16x8*)&gbh[k0 + 8];
        }
        __syncthreads();

        f16x8 ah[2], bh[4];
#pragma unroll
        for (int mf = 0; mf < 2; ++mf)
            ah[mf] = *(const f16x8*)&sA[(wm + mf * 16 + lm) * 40 + quad * 8];
#pragma unroll
        for (int nf = 0; nf < 4; ++nf)
            bh[nf] = *(const f16x8*)&sB[(wn + nf * 16 + lm) * 40 + quad * 8];
#pragma unroll
        for (int mf = 0; mf < 2; ++mf)
#pragma unroll
            for (int nf = 0; nf < 4; ++nf)
                acc[mf][nf] = __builtin_amdgcn_mfma_f32_16x16x32_f16(ah[mf], bh[nf], acc[mf][nf], 0, 0, 0);
    }

#pragma unroll
    for (int mf = 0; mf < 2; ++mf)
#pragma unroll
        for (int r = 0; r < 4; ++r) {
            const size_t m = (size_t)(mt * 64 + wm + mf * 16 + quad * 4 + r);
#pragma unroll
            for (int nf = 0; nf < 4; ++nf) {
                const int col = nt * 128 + wn + nf * 16 + lm;
                Outp[m * Cc + col] = acc[mf][nf][r] + bo[col] + HS[m * Cc + col];
            }
        }
}

// ---------------------------------------------------------------------------
extern "C" void kernel_launch(void* const* d_in, const int* in_sizes, int n_in,
                              void* d_out, int out_size, void* d_ws,
                              size_t ws_size, hipStream_t stream)
{
    const float* HS = (const float*)d_in[0];
    const float* Wq = (const float*)d_in[1];
    const float* Wk = (const float*)d_in[2];
    const float* Wv = (const float*)d_in[3];
    const float* Wo = (const float*)d_in[4];
    const float* bo = (const float*)d_in[5];
    float* out = (float*)d_out;

    const size_t SZ = (size_t)Bb * Tt * Cc;        // 4,194,304 elements
    _Float16* Qf  = (_Float16*)d_ws;
    _Float16* Kf  = Qf + SZ;
    _Float16* Vf  = Kf + SZ;
    _Float16* VTh = Vf + SZ;
    _Float16* AO  = VTh + SZ;
    _Float16* Wt  = AO + SZ;                        // 4*Cc*Cc halves
    float* colsum = (float*)(Wt + 4 * Cc * Cc);
    float* inv    = colsum + 3 * BC;

    hipMemsetAsync(colsum, 0, 3 * BC * sizeof(float), stream);

    wsetup<<<dim3(64, 4), 256, 0, stream>>>(Wq, Wk, Wv, Wo, Wt);

    qkv_mfma<<<dim3(64, 4, 3), 256, 0, stream>>>(HS, Wt, Qf, Kf, Vf, colsum);

    inv_norm_kernel<<<(3 * BC + 255) / 256, 256, 0, stream>>>(colsum, inv);

    norm_vt<<<1024, 256, 0, stream>>>(Vf, VTh);

    attn_mfma<<<dim3(16, 32), 256, 0, stream>>>(Qf, Kf, VTh, inv, AO);

    out_mfma<<<dim3(128, 4), 256, 0, stream>>>(AO, Wt, bo, HS, out);
}